// Round 1
// baseline (734.041 us; speedup 1.0000x reference)
//
#include <hip/hip_runtime.h>
#include <hip/hip_fp16.h>
#include <stdint.h>

#define N_NODES   100000
#define N_EDGES   3200000
#define F_IN      128
#define F_HID     64
#define F_OUT     16

// ---- workspace layout (bytes), all offsets 16B-aligned ----
#define OFF_CNT      0                        // int[N]          counts by dst
#define OFF_CURSOR   (OFF_CNT + 400000)       // int[N]          scatter cursors
#define OFF_ROWSTART (OFF_CURSOR + 400000)    // int[N+1]        CSR row starts
#define OFF_DINV     (OFF_ROWSTART + 400016)  // float[N]        1/sqrt(deg)
#define OFF_BSUM     (OFF_DINV + 400000)      // int[128]        scan block sums
#define OFF_FLAG     (OFF_BSUM + 512)         // int             1 if edge_index is int64
#define OFF_CSR      (OFF_FLAG + 16)          // int[E]          src per CSR slot
#define OFF_HS1      (OFF_CSR + 12800000)     // half[N*64]      dinv-scaled h1
#define OFF_OUT1     (OFF_HS1 + 12800000)     // float[N*64]     relu'd layer-1 out
#define OFF_HS2      (OFF_OUT1 + 25600000)    // half[N*16]      dinv-scaled h2
// total = 56,000,544 bytes

// ---------------- edge dtype detection + loaders ----------------
__global__ void k_detect(const void* __restrict__ ei, int* __restrict__ flag) {
    // int64 data viewed as u32 pairs: [lo<100000, hi==0] x 64. For genuine
    // int32 data the "hi" words are random values in [0,100000): P(all 0)~0.
    const unsigned* u = (const unsigned*)ei;
    int ok = 1;
    for (int i = 0; i < 64; ++i) {
        unsigned lo = u[2 * i], hi = u[2 * i + 1];
        if (hi != 0u || lo >= 100000u) { ok = 0; break; }
    }
    *flag = ok;
}

__device__ __forceinline__ int edge_src(const void* ei, int is64, int e) {
    return is64 ? (int)((const long long*)ei)[e] : ((const int*)ei)[e];
}
__device__ __forceinline__ int edge_dst(const void* ei, int is64, int e) {
    return is64 ? (int)((const long long*)ei)[N_EDGES + e]
                : ((const int*)ei)[N_EDGES + e];
}

// ---------------- degree histogram + dinv ----------------
__global__ __launch_bounds__(256) void k_hist(const void* __restrict__ ei,
                                              const int* __restrict__ flag,
                                              int* __restrict__ cnt) {
    int e = blockIdx.x * 256 + threadIdx.x;   // grid covers E exactly
    int is64 = *flag;
    atomicAdd(&cnt[edge_dst(ei, is64, e)], 1);
}

__global__ __launch_bounds__(256) void k_dinv(const int* __restrict__ cnt,
                                              float* __restrict__ dinv) {
    int i = blockIdx.x * 256 + threadIdx.x;
    if (i < N_NODES) dinv[i] = rsqrtf((float)cnt[i] + 1.0f);
}

// ---------------- exclusive scan of cnt -> rowstart (chunk=1024, NB=98) ----------------
__global__ __launch_bounds__(256) void k_scan_partial(const int* __restrict__ cnt,
                                                      int* __restrict__ bsum) {
    __shared__ int sd[256];
    int t = threadIdx.x;
    int base = blockIdx.x * 1024 + t * 4;
    int s = 0;
#pragma unroll
    for (int c = 0; c < 4; ++c)
        if (base + c < N_NODES) s += cnt[base + c];
    sd[t] = s;
    __syncthreads();
    for (int off = 128; off > 0; off >>= 1) {
        if (t < off) sd[t] += sd[t + off];
        __syncthreads();
    }
    if (t == 0) bsum[blockIdx.x] = sd[0];
}

__global__ void k_scan_bsums(int* __restrict__ bsum) {  // <<<1,128>>>, NB=98
    __shared__ int sd[128];
    int t = threadIdx.x;
    sd[t] = (t < 98) ? bsum[t] : 0;
    __syncthreads();
    for (int off = 1; off < 128; off <<= 1) {
        int add = (t >= off) ? sd[t - off] : 0;
        __syncthreads();
        sd[t] += add;
        __syncthreads();
    }
    if (t < 98) bsum[t] = (t == 0) ? 0 : sd[t - 1];
}

__global__ __launch_bounds__(256) void k_scan_final(const int* __restrict__ cnt,
                                                    const int* __restrict__ bsum,
                                                    int* __restrict__ rowstart) {
    __shared__ int sd[256];
    int t = threadIdx.x;
    int base = blockIdx.x * 1024 + t * 4;
    int v[4];
#pragma unroll
    for (int c = 0; c < 4; ++c)
        v[c] = (base + c < N_NODES) ? cnt[base + c] : 0;
    int tsum = v[0] + v[1] + v[2] + v[3];
    sd[t] = tsum;
    __syncthreads();
    for (int off = 1; off < 256; off <<= 1) {
        int add = (t >= off) ? sd[t - off] : 0;
        __syncthreads();
        sd[t] += add;
        __syncthreads();
    }
    int run = bsum[blockIdx.x] + sd[t] - tsum;
#pragma unroll
    for (int c = 0; c < 4; ++c) {
        if (base + c < N_NODES) rowstart[base + c] = run;
        run += v[c];
    }
    if (blockIdx.x == 0 && t == 0) rowstart[N_NODES] = N_EDGES;
}

// ---------------- scatter edges into CSR slots ----------------
__global__ __launch_bounds__(256) void k_scatter(const void* __restrict__ ei,
                                                 const int* __restrict__ flag,
                                                 const int* __restrict__ rowstart,
                                                 int* __restrict__ cursor,
                                                 int* __restrict__ csr) {
    int e = blockIdx.x * 256 + threadIdx.x;   // grid covers E exactly
    int is64 = *flag;
    int s = edge_src(ei, is64, e);
    int d = edge_dst(ei, is64, e);
    int pos = rowstart[d] + atomicAdd(&cursor[d], 1);
    csr[pos] = s;
}

// ---------------- GEMM1: hs1 = (x @ W1) * dinv[row], fp16 out ----------------
__global__ __launch_bounds__(256) void k_gemm1(const float* __restrict__ x,
                                               const float* __restrict__ W1,
                                               const float* __restrict__ dinv,
                                               __half* __restrict__ hs1) {
    int tid = blockIdx.x * 256 + threadIdx.x;  // N*16 threads exactly
    int n = tid >> 4;
    int jq = (tid & 15) << 2;
    const float4* x4 = (const float4*)(x + (size_t)n * F_IN);
    const float4* w4 = (const float4*)(W1 + jq);  // row k -> w4[k*16]
    float4 acc = make_float4(0.f, 0.f, 0.f, 0.f);
#pragma unroll 4
    for (int k4 = 0; k4 < 32; ++k4) {
        float4 xv = x4[k4];
        float4 w0 = w4[(k4 * 4 + 0) * 16];
        float4 w1 = w4[(k4 * 4 + 1) * 16];
        float4 w2 = w4[(k4 * 4 + 2) * 16];
        float4 w3 = w4[(k4 * 4 + 3) * 16];
        acc.x += xv.x * w0.x + xv.y * w1.x + xv.z * w2.x + xv.w * w3.x;
        acc.y += xv.x * w0.y + xv.y * w1.y + xv.z * w2.y + xv.w * w3.y;
        acc.z += xv.x * w0.z + xv.y * w1.z + xv.z * w2.z + xv.w * w3.z;
        acc.w += xv.x * w0.w + xv.y * w1.w + xv.z * w2.w + xv.w * w3.w;
    }
    float dv = dinv[n];
    union { __half2 h[2]; float2 f; } u;
    u.h[0] = __floats2half2_rn(acc.x * dv, acc.y * dv);
    u.h[1] = __floats2half2_rn(acc.z * dv, acc.w * dv);
    *(float2*)(hs1 + (size_t)n * F_HID + jq) = u.f;
}

// ---------------- gather layer 1: wave per node, lane = feature ----------------
__global__ __launch_bounds__(256) void k_gather1(const __half* __restrict__ hs1,
                                                 const int* __restrict__ csr,
                                                 const int* __restrict__ rowstart,
                                                 const float* __restrict__ dinv,
                                                 const float* __restrict__ b1,
                                                 float* __restrict__ out1) {
    int w = threadIdx.x >> 6;
    int lane = threadIdx.x & 63;
    int n = blockIdx.x * 4 + w;               // grid = 25000 -> exact
    int s0 = rowstart[n], s1 = rowstart[n + 1];
    float acc = __half2float(hs1[(size_t)n * F_HID + lane]);  // self-loop
    int e = s0;
    for (; e + 4 <= s1; e += 4) {
        int a = csr[e], b = csr[e + 1], c = csr[e + 2], d = csr[e + 3];
        float va = __half2float(hs1[(size_t)a * F_HID + lane]);
        float vb = __half2float(hs1[(size_t)b * F_HID + lane]);
        float vc = __half2float(hs1[(size_t)c * F_HID + lane]);
        float vd = __half2float(hs1[(size_t)d * F_HID + lane]);
        acc += va + vb + vc + vd;
    }
    for (; e < s1; ++e)
        acc += __half2float(hs1[(size_t)csr[e] * F_HID + lane]);
    float o = dinv[n] * acc + b1[lane];
    out1[(size_t)n * F_HID + lane] = fmaxf(0.f, o);
}

// ---------------- GEMM2: hs2 = (out1 @ W2) * dinv[row], fp16 out ----------------
__global__ __launch_bounds__(256) void k_gemm2(const float* __restrict__ h,
                                               const float* __restrict__ W2,
                                               const float* __restrict__ dinv,
                                               __half* __restrict__ hs2) {
    int tid = blockIdx.x * 256 + threadIdx.x;  // N*4 threads (guarded)
    int n = tid >> 2;
    if (n >= N_NODES) return;
    int cq = (tid & 3) << 2;
    const float4* h4 = (const float4*)(h + (size_t)n * F_HID);
    const float4* w4 = (const float4*)(W2 + cq);  // row k -> w4[k*4]
    float4 acc = make_float4(0.f, 0.f, 0.f, 0.f);
#pragma unroll 4
    for (int k4 = 0; k4 < 16; ++k4) {
        float4 hv = h4[k4];
        float4 w0 = w4[(k4 * 4 + 0) * 4];
        float4 w1 = w4[(k4 * 4 + 1) * 4];
        float4 w2 = w4[(k4 * 4 + 2) * 4];
        float4 w3 = w4[(k4 * 4 + 3) * 4];
        acc.x += hv.x * w0.x + hv.y * w1.x + hv.z * w2.x + hv.w * w3.x;
        acc.y += hv.x * w0.y + hv.y * w1.y + hv.z * w2.y + hv.w * w3.y;
        acc.z += hv.x * w0.z + hv.y * w1.z + hv.z * w2.z + hv.w * w3.z;
        acc.w += hv.x * w0.w + hv.y * w1.w + hv.z * w2.w + hv.w * w3.w;
    }
    float dv = dinv[n];
    union { __half2 h2[2]; float2 f; } u;
    u.h2[0] = __floats2half2_rn(acc.x * dv, acc.y * dv);
    u.h2[1] = __floats2half2_rn(acc.z * dv, acc.w * dv);
    *(float2*)(hs2 + (size_t)n * F_OUT + cq) = u.f;
}

// ---------------- gather layer 2: wave per node, 4 edges x 16 feats ----------------
__global__ __launch_bounds__(256) void k_gather2(const __half* __restrict__ hs2,
                                                 const int* __restrict__ csr,
                                                 const int* __restrict__ rowstart,
                                                 const float* __restrict__ dinv,
                                                 const float* __restrict__ b2,
                                                 float* __restrict__ out) {
    int w = threadIdx.x >> 6;
    int lane = threadIdx.x & 63;
    int n = blockIdx.x * 4 + w;               // grid = 25000 -> exact
    int esub = lane >> 4;                      // 0..3
    int c = lane & 15;
    int s0 = rowstart[n], s1 = rowstart[n + 1];
    float acc = 0.f;
    for (int e = s0 + esub; e < s1; e += 4) {
        int s = csr[e];
        acc += __half2float(hs2[(size_t)s * F_OUT + c]);
    }
    acc += __shfl_xor(acc, 16);
    acc += __shfl_xor(acc, 32);
    if (lane < 16) {
        float self = __half2float(hs2[(size_t)n * F_OUT + c]);
        out[(size_t)n * F_OUT + c] = dinv[n] * (acc + self) + b2[c];
    }
}

extern "C" void kernel_launch(void* const* d_in, const int* in_sizes, int n_in,
                              void* d_out, int out_size, void* d_ws, size_t ws_size,
                              hipStream_t stream) {
    const float* x  = (const float*)d_in[0];
    const void*  ei = d_in[1];
    const float* W1 = (const float*)d_in[2];
    const float* b1 = (const float*)d_in[3];
    const float* W2 = (const float*)d_in[4];
    const float* b2 = (const float*)d_in[5];
    float* out = (float*)d_out;

    char* ws = (char*)d_ws;
    int*    cnt      = (int*)(ws + OFF_CNT);
    int*    cursor   = (int*)(ws + OFF_CURSOR);
    int*    rowstart = (int*)(ws + OFF_ROWSTART);
    float*  dinv     = (float*)(ws + OFF_DINV);
    int*    bsum     = (int*)(ws + OFF_BSUM);
    int*    flag     = (int*)(ws + OFF_FLAG);
    int*    csr      = (int*)(ws + OFF_CSR);
    __half* hs1      = (__half*)(ws + OFF_HS1);
    float*  out1     = (float*)(ws + OFF_OUT1);
    __half* hs2      = (__half*)(ws + OFF_HS2);

    k_detect<<<1, 1, 0, stream>>>(ei, flag);
    // cnt and cursor are adjacent: one memset clears both
    hipMemsetAsync(ws + OFF_CNT, 0, 800000, stream);

    k_hist<<<N_EDGES / 256, 256, 0, stream>>>(ei, flag, cnt);
    k_dinv<<<(N_NODES + 255) / 256, 256, 0, stream>>>(cnt, dinv);

    k_scan_partial<<<98, 256, 0, stream>>>(cnt, bsum);
    k_scan_bsums<<<1, 128, 0, stream>>>(bsum);
    k_scan_final<<<98, 256, 0, stream>>>(cnt, bsum, rowstart);

    k_scatter<<<N_EDGES / 256, 256, 0, stream>>>(ei, flag, rowstart, cursor, csr);

    k_gemm1<<<N_NODES * 16 / 256, 256, 0, stream>>>(x, W1, dinv, hs1);
    k_gather1<<<N_NODES / 4, 256, 0, stream>>>(hs1, csr, rowstart, dinv, b1, out1);
    k_gemm2<<<(N_NODES * 4 + 255) / 256, 256, 0, stream>>>(out1, W2, dinv, hs2);
    k_gather2<<<N_NODES / 4, 256, 0, stream>>>(hs2, csr, rowstart, dinv, b2, out);
}

// Round 2
// 543.495 us; speedup vs baseline: 1.3506x; 1.3506x over previous
//
#include <hip/hip_runtime.h>
#include <hip/hip_fp16.h>
#include <stdint.h>

#define N_NODES   100000
#define N_EDGES   3200000
#define F_IN      128
#define F_HID     64
#define F_OUT     16

// bucket partition params
#define BSHIFT    8
#define NBUCK     391            // ceil(100000 / 256)
#define NBLK_P    128            // partition blocks
#define CHUNK     (N_EDGES / NBLK_P)   // 25000 edges per block

// ---- workspace layout (bytes), all offsets 16B-aligned ----
#define OFF_CNT      0                         // int[N]
#define OFF_ROWSTART 400000                    // int[N+1]
#define OFF_DINV     800016                    // float[N]
#define OFF_BSUM     1200016                   // int[128]
#define OFF_FLAG     1200528                   // int
#define OFF_BSTART   1200544                   // int[NBUCK+1]
#define OFF_BHIST    1202128                   // int[NBUCK*NBLK_P]
#define OFF_CSR      1402320                   // int[E]
#define OFF_HS1      (OFF_CSR + 12800000)      // half[N*64]
#define OFF_OUT1     (OFF_HS1 + 12800000)      // float[N*64]
#define OFF_HS2      (OFF_OUT1 + 25600000)     // half[N*16]
#define OFF_PAIRS    OFF_OUT1                  // uint2[E] — aliases out1 (dead by then)
// total = 55,802,320 bytes

// ---------------- edge dtype detection + loaders ----------------
__global__ void k_detect(const void* __restrict__ ei, int* __restrict__ flag) {
    const unsigned* u = (const unsigned*)ei;
    int ok = 1;
    for (int i = 0; i < 64; ++i) {
        unsigned lo = u[2 * i], hi = u[2 * i + 1];
        if (hi != 0u || lo >= 100000u) { ok = 0; break; }
    }
    *flag = ok;   // 1 => int64 edge data
}

__device__ __forceinline__ int edge_src(const void* ei, int is64, int e) {
    return is64 ? (int)((const long long*)ei)[e] : ((const int*)ei)[e];
}
__device__ __forceinline__ int edge_dst(const void* ei, int is64, int e) {
    return is64 ? (int)((const long long*)ei)[N_EDGES + e]
                : ((const int*)ei)[N_EDGES + e];
}

// ---------------- pass 1: per-block bucket histogram ----------------
__global__ __launch_bounds__(256) void k_bhist(const void* __restrict__ ei,
                                               const int* __restrict__ flag,
                                               int* __restrict__ bhist) {
    __shared__ int h[NBUCK];
    for (int i = threadIdx.x; i < NBUCK; i += 256) h[i] = 0;
    __syncthreads();
    int is64 = *flag;
    int base = blockIdx.x * CHUNK;
    for (int i = threadIdx.x; i < CHUNK; i += 256)
        atomicAdd(&h[edge_dst(ei, is64, base + i) >> BSHIFT], 1);
    __syncthreads();
    for (int i = threadIdx.x; i < NBUCK; i += 256)
        bhist[i * NBLK_P + blockIdx.x] = h[i];
}

// ---------------- pass 2a: bucket totals -> exclusive bucket starts ----------------
__global__ __launch_bounds__(512) void k_bstart(const int* __restrict__ bhist,
                                                int* __restrict__ bstart) {
    __shared__ int sd[512];
    int t = threadIdx.x;
    int s = 0;
    if (t < NBUCK) {
        const int* p = bhist + t * NBLK_P;
        for (int i = 0; i < NBLK_P; ++i) s += p[i];
    }
    sd[t] = s;
    __syncthreads();
    for (int off = 1; off < 512; off <<= 1) {
        int add = (t >= off) ? sd[t - off] : 0;
        __syncthreads();
        sd[t] += add;
        __syncthreads();
    }
    if (t < NBUCK) bstart[t] = sd[t] - s;
    if (t == 0) bstart[NBUCK] = N_EDGES;
}

// ---------------- pass 2b: per-bucket scan of per-block counts -> write offsets ----------------
__global__ __launch_bounds__(128) void k_boffs(int* __restrict__ bhist,
                                               const int* __restrict__ bstart) {
    __shared__ int sd[128];
    int b = blockIdx.x, t = threadIdx.x;
    int v = bhist[b * NBLK_P + t];
    sd[t] = v;
    __syncthreads();
    for (int off = 1; off < 128; off <<= 1) {
        int add = (t >= off) ? sd[t - off] : 0;
        __syncthreads();
        sd[t] += add;
        __syncthreads();
    }
    bhist[b * NBLK_P + t] = bstart[b] + sd[t] - v;
}

// ---------------- pass 3: partition edges into bucket-grouped (src,dst) pairs ----------------
__global__ __launch_bounds__(256) void k_partition(const void* __restrict__ ei,
                                                   const int* __restrict__ flag,
                                                   const int* __restrict__ bhist,
                                                   uint2* __restrict__ pairs) {
    __shared__ int cur[NBUCK];
    for (int i = threadIdx.x; i < NBUCK; i += 256)
        cur[i] = bhist[i * NBLK_P + blockIdx.x];
    __syncthreads();
    int is64 = *flag;
    int base = blockIdx.x * CHUNK;
    for (int i = threadIdx.x; i < CHUNK; i += 256) {
        int e = base + i;
        int s = edge_src(ei, is64, e);
        int d = edge_dst(ei, is64, e);
        int p = atomicAdd(&cur[d >> BSHIFT], 1);
        pairs[p] = make_uint2((unsigned)s, (unsigned)d);
    }
}

// ---------------- pass 4: per-bucket dst counts (coalesced cnt write) ----------------
__global__ __launch_bounds__(256) void k_dcount(const uint2* __restrict__ pairs,
                                                const int* __restrict__ bstart,
                                                int* __restrict__ cnt) {
    __shared__ int c[256];
    int b = blockIdx.x, t = threadIdx.x;
    c[t] = 0;
    __syncthreads();
    int s0 = bstart[b], s1 = bstart[b + 1];
    int dbase = b << BSHIFT;
    for (int i = s0 + t; i < s1; i += 256)
        atomicAdd(&c[pairs[i].y - dbase], 1);
    __syncthreads();
    int d = dbase + t;
    if (d < N_NODES) cnt[d] = c[t];
}

__global__ __launch_bounds__(256) void k_dinv(const int* __restrict__ cnt,
                                              float* __restrict__ dinv) {
    int i = blockIdx.x * 256 + threadIdx.x;
    if (i < N_NODES) dinv[i] = rsqrtf((float)cnt[i] + 1.0f);
}

// ---------------- exclusive scan of cnt -> rowstart (chunk=1024, NB=98) ----------------
__global__ __launch_bounds__(256) void k_scan_partial(const int* __restrict__ cnt,
                                                      int* __restrict__ bsum) {
    __shared__ int sd[256];
    int t = threadIdx.x;
    int base = blockIdx.x * 1024 + t * 4;
    int s = 0;
#pragma unroll
    for (int c = 0; c < 4; ++c)
        if (base + c < N_NODES) s += cnt[base + c];
    sd[t] = s;
    __syncthreads();
    for (int off = 128; off > 0; off >>= 1) {
        if (t < off) sd[t] += sd[t + off];
        __syncthreads();
    }
    if (t == 0) bsum[blockIdx.x] = sd[0];
}

__global__ void k_scan_bsums(int* __restrict__ bsum) {  // <<<1,128>>>, NB=98
    __shared__ int sd[128];
    int t = threadIdx.x;
    sd[t] = (t < 98) ? bsum[t] : 0;
    __syncthreads();
    for (int off = 1; off < 128; off <<= 1) {
        int add = (t >= off) ? sd[t - off] : 0;
        __syncthreads();
        sd[t] += add;
        __syncthreads();
    }
    if (t < 98) bsum[t] = (t == 0) ? 0 : sd[t - 1];
}

__global__ __launch_bounds__(256) void k_scan_final(const int* __restrict__ cnt,
                                                    const int* __restrict__ bsum,
                                                    int* __restrict__ rowstart) {
    __shared__ int sd[256];
    int t = threadIdx.x;
    int base = blockIdx.x * 1024 + t * 4;
    int v[4];
#pragma unroll
    for (int c = 0; c < 4; ++c)
        v[c] = (base + c < N_NODES) ? cnt[base + c] : 0;
    int tsum = v[0] + v[1] + v[2] + v[3];
    sd[t] = tsum;
    __syncthreads();
    for (int off = 1; off < 256; off <<= 1) {
        int add = (t >= off) ? sd[t - off] : 0;
        __syncthreads();
        sd[t] += add;
        __syncthreads();
    }
    int run = bsum[blockIdx.x] + sd[t] - tsum;
#pragma unroll
    for (int c = 0; c < 4; ++c) {
        if (base + c < N_NODES) rowstart[base + c] = run;
        run += v[c];
    }
    if (blockIdx.x == 0 && t == 0) rowstart[N_NODES] = N_EDGES;
}

// ---------------- pass 5: final CSR placement (LDS cursors, 32KB write window) ----------------
__global__ __launch_bounds__(256) void k_place(const uint2* __restrict__ pairs,
                                               const int* __restrict__ bstart,
                                               const int* __restrict__ rowstart,
                                               int* __restrict__ csr) {
    __shared__ int pos[256];
    int b = blockIdx.x, t = threadIdx.x;
    int dbase = b << BSHIFT;
    int d = dbase + t;
    pos[t] = (d < N_NODES) ? rowstart[d] : 0;
    __syncthreads();
    int s0 = bstart[b], s1 = bstart[b + 1];
    for (int i = s0 + t; i < s1; i += 256) {
        uint2 pr = pairs[i];
        int p = atomicAdd(&pos[pr.y - dbase], 1);
        csr[p] = (int)pr.x;
    }
}

// ---------------- GEMM1: hs1 = (x @ W1) * dinv[row], fp16 out ----------------
__global__ __launch_bounds__(256) void k_gemm1(const float* __restrict__ x,
                                               const float* __restrict__ W1,
                                               const float* __restrict__ dinv,
                                               __half* __restrict__ hs1) {
    int tid = blockIdx.x * 256 + threadIdx.x;  // N*16 threads exactly
    int n = tid >> 4;
    int jq = (tid & 15) << 2;
    const float4* x4 = (const float4*)(x + (size_t)n * F_IN);
    const float4* w4 = (const float4*)(W1 + jq);
    float4 acc = make_float4(0.f, 0.f, 0.f, 0.f);
#pragma unroll 4
    for (int k4 = 0; k4 < 32; ++k4) {
        float4 xv = x4[k4];
        float4 w0 = w4[(k4 * 4 + 0) * 16];
        float4 w1 = w4[(k4 * 4 + 1) * 16];
        float4 w2 = w4[(k4 * 4 + 2) * 16];
        float4 w3 = w4[(k4 * 4 + 3) * 16];
        acc.x += xv.x * w0.x + xv.y * w1.x + xv.z * w2.x + xv.w * w3.x;
        acc.y += xv.x * w0.y + xv.y * w1.y + xv.z * w2.y + xv.w * w3.y;
        acc.z += xv.x * w0.z + xv.y * w1.z + xv.z * w2.z + xv.w * w3.z;
        acc.w += xv.x * w0.w + xv.y * w1.w + xv.z * w2.w + xv.w * w3.w;
    }
    float dv = dinv[n];
    union { __half2 h[2]; float2 f; } u;
    u.h[0] = __floats2half2_rn(acc.x * dv, acc.y * dv);
    u.h[1] = __floats2half2_rn(acc.z * dv, acc.w * dv);
    *(float2*)(hs1 + (size_t)n * F_HID + jq) = u.f;
}

// ---------------- gather layer 1: wave per node, lane = feature ----------------
__global__ __launch_bounds__(256) void k_gather1(const __half* __restrict__ hs1,
                                                 const int* __restrict__ csr,
                                                 const int* __restrict__ rowstart,
                                                 const float* __restrict__ dinv,
                                                 const float* __restrict__ b1,
                                                 float* __restrict__ out1) {
    int w = threadIdx.x >> 6;
    int lane = threadIdx.x & 63;
    int n = blockIdx.x * 4 + w;
    int s0 = rowstart[n], s1 = rowstart[n + 1];
    float acc = __half2float(hs1[(size_t)n * F_HID + lane]);  // self-loop
    int e = s0;
    for (; e + 4 <= s1; e += 4) {
        int a = csr[e], b = csr[e + 1], c = csr[e + 2], d = csr[e + 3];
        float va = __half2float(hs1[(size_t)a * F_HID + lane]);
        float vb = __half2float(hs1[(size_t)b * F_HID + lane]);
        float vc = __half2float(hs1[(size_t)c * F_HID + lane]);
        float vd = __half2float(hs1[(size_t)d * F_HID + lane]);
        acc += va + vb + vc + vd;
    }
    for (; e < s1; ++e)
        acc += __half2float(hs1[(size_t)csr[e] * F_HID + lane]);
    float o = dinv[n] * acc + b1[lane];
    out1[(size_t)n * F_HID + lane] = fmaxf(0.f, o);
}

// ---------------- GEMM2: hs2 = (out1 @ W2) * dinv[row], fp16 out ----------------
__global__ __launch_bounds__(256) void k_gemm2(const float* __restrict__ h,
                                               const float* __restrict__ W2,
                                               const float* __restrict__ dinv,
                                               __half* __restrict__ hs2) {
    int tid = blockIdx.x * 256 + threadIdx.x;
    int n = tid >> 2;
    if (n >= N_NODES) return;
    int cq = (tid & 3) << 2;
    const float4* h4 = (const float4*)(h + (size_t)n * F_HID);
    const float4* w4 = (const float4*)(W2 + cq);
    float4 acc = make_float4(0.f, 0.f, 0.f, 0.f);
#pragma unroll 4
    for (int k4 = 0; k4 < 16; ++k4) {
        float4 hv = h4[k4];
        float4 w0 = w4[(k4 * 4 + 0) * 4];
        float4 w1 = w4[(k4 * 4 + 1) * 4];
        float4 w2 = w4[(k4 * 4 + 2) * 4];
        float4 w3 = w4[(k4 * 4 + 3) * 4];
        acc.x += hv.x * w0.x + hv.y * w1.x + hv.z * w2.x + hv.w * w3.x;
        acc.y += hv.x * w0.y + hv.y * w1.y + hv.z * w2.y + hv.w * w3.y;
        acc.z += hv.x * w0.z + hv.y * w1.z + hv.z * w2.z + hv.w * w3.z;
        acc.w += hv.x * w0.w + hv.y * w1.w + hv.z * w2.w + hv.w * w3.w;
    }
    float dv = dinv[n];
    union { __half2 h2[2]; float2 f; } u;
    u.h2[0] = __floats2half2_rn(acc.x * dv, acc.y * dv);
    u.h2[1] = __floats2half2_rn(acc.z * dv, acc.w * dv);
    *(float2*)(hs2 + (size_t)n * F_OUT + cq) = u.f;
}

// ---------------- gather layer 2: wave per node, 4 edges x 16 feats ----------------
__global__ __launch_bounds__(256) void k_gather2(const __half* __restrict__ hs2,
                                                 const int* __restrict__ csr,
                                                 const int* __restrict__ rowstart,
                                                 const float* __restrict__ dinv,
                                                 const float* __restrict__ b2,
                                                 float* __restrict__ out) {
    int w = threadIdx.x >> 6;
    int lane = threadIdx.x & 63;
    int n = blockIdx.x * 4 + w;
    int esub = lane >> 4;
    int c = lane & 15;
    int s0 = rowstart[n], s1 = rowstart[n + 1];
    float acc = 0.f;
    for (int e = s0 + esub; e < s1; e += 4) {
        int s = csr[e];
        acc += __half2float(hs2[(size_t)s * F_OUT + c]);
    }
    acc += __shfl_xor(acc, 16);
    acc += __shfl_xor(acc, 32);
    if (lane < 16) {
        float self = __half2float(hs2[(size_t)n * F_OUT + c]);
        out[(size_t)n * F_OUT + c] = dinv[n] * (acc + self) + b2[c];
    }
}

extern "C" void kernel_launch(void* const* d_in, const int* in_sizes, int n_in,
                              void* d_out, int out_size, void* d_ws, size_t ws_size,
                              hipStream_t stream) {
    const float* x  = (const float*)d_in[0];
    const void*  ei = d_in[1];
    const float* W1 = (const float*)d_in[2];
    const float* b1 = (const float*)d_in[3];
    const float* W2 = (const float*)d_in[4];
    const float* b2 = (const float*)d_in[5];
    float* out = (float*)d_out;

    char* ws = (char*)d_ws;
    int*    cnt      = (int*)(ws + OFF_CNT);
    int*    rowstart = (int*)(ws + OFF_ROWSTART);
    float*  dinv     = (float*)(ws + OFF_DINV);
    int*    bsum     = (int*)(ws + OFF_BSUM);
    int*    flag     = (int*)(ws + OFF_FLAG);
    int*    bstart   = (int*)(ws + OFF_BSTART);
    int*    bhist    = (int*)(ws + OFF_BHIST);
    int*    csr      = (int*)(ws + OFF_CSR);
    __half* hs1      = (__half*)(ws + OFF_HS1);
    float*  out1     = (float*)(ws + OFF_OUT1);
    __half* hs2      = (__half*)(ws + OFF_HS2);
    uint2*  pairs    = (uint2*)(ws + OFF_PAIRS);   // aliases out1 (dead until gather1)

    k_detect<<<1, 1, 0, stream>>>(ei, flag);

    // CSR build: bucket partition (no global atomics, coalesced writes)
    k_bhist    <<<NBLK_P, 256, 0, stream>>>(ei, flag, bhist);
    k_bstart   <<<1, 512, 0, stream>>>(bhist, bstart);
    k_boffs    <<<NBUCK, 128, 0, stream>>>(bhist, bstart);
    k_partition<<<NBLK_P, 256, 0, stream>>>(ei, flag, bhist, pairs);
    k_dcount   <<<NBUCK, 256, 0, stream>>>(pairs, bstart, cnt);
    k_dinv     <<<(N_NODES + 255) / 256, 256, 0, stream>>>(cnt, dinv);
    k_scan_partial<<<98, 256, 0, stream>>>(cnt, bsum);
    k_scan_bsums  <<<1, 128, 0, stream>>>(bsum);
    k_scan_final  <<<98, 256, 0, stream>>>(cnt, bsum, rowstart);
    k_place    <<<NBUCK, 256, 0, stream>>>(pairs, bstart, rowstart, csr);

    // GCN layers
    k_gemm1  <<<N_NODES * 16 / 256, 256, 0, stream>>>(x, W1, dinv, hs1);
    k_gather1<<<N_NODES / 4, 256, 0, stream>>>(hs1, csr, rowstart, dinv, b1, out1);
    k_gemm2  <<<(N_NODES * 4 + 255) / 256, 256, 0, stream>>>(out1, W2, dinv, hs2);
    k_gather2<<<N_NODES / 4, 256, 0, stream>>>(hs2, csr, rowstart, dinv, b2, out);
}

// Round 3
// 462.511 us; speedup vs baseline: 1.5871x; 1.1751x over previous
//
#include <hip/hip_runtime.h>
#include <hip/hip_fp16.h>
#include <stdint.h>

#define N_NODES   100000
#define N_EDGES   3200000
#define F_IN      128
#define F_HID     64
#define F_OUT     16

// bucket partition params
#define BSHIFT    8
#define NBUCK     391            // ceil(100000 / 256)
#define NBLK_P    128            // partition blocks
#define CHUNK     (N_EDGES / NBLK_P)   // 25000 edges per block

// gemm1 tiling
#define G1_TM     128            // nodes per block
#define G1_BLOCKS ((N_NODES + G1_TM - 1) / G1_TM)   // 782
#define XS_LD     132            // 128 + 4 pad (floats), k-major rows

// ---- workspace layout (bytes), all offsets 16B-aligned ----
#define OFF_CNT      0                         // int[N]
#define OFF_ROWSTART 400000                    // int[N+1]
#define OFF_DINV     800016                    // float[N]
#define OFF_BSUM     1200016                   // int[128]
#define OFF_FLAG     1200528                   // int
#define OFF_BSTART   1200544                   // int[NBUCK+1]
#define OFF_BHIST    1202128                   // int[NBUCK*NBLK_P]
#define OFF_CSR      1402320                   // int[E]
#define OFF_HS1      (OFF_CSR + 12800000)      // half[N*64]
#define OFF_OUT1     (OFF_HS1 + 12800000)      // float[N*64]
#define OFF_HS2      (OFF_OUT1 + 25600000)     // half[N*16]
#define OFF_PAIRS    OFF_OUT1                  // uint2[E] — aliases out1 (dead by then)

// ---------------- edge dtype detection + loaders ----------------
__global__ void k_detect(const void* __restrict__ ei, int* __restrict__ flag) {
    const unsigned* u = (const unsigned*)ei;
    int ok = 1;
    for (int i = 0; i < 64; ++i) {
        unsigned lo = u[2 * i], hi = u[2 * i + 1];
        if (hi != 0u || lo >= 100000u) { ok = 0; break; }
    }
    *flag = ok;   // 1 => int64 edge data
}

__device__ __forceinline__ int edge_src(const void* ei, int is64, int e) {
    return is64 ? (int)((const long long*)ei)[e] : ((const int*)ei)[e];
}
__device__ __forceinline__ int edge_dst(const void* ei, int is64, int e) {
    return is64 ? (int)((const long long*)ei)[N_EDGES + e]
                : ((const int*)ei)[N_EDGES + e];
}

// ---------------- pass 1: per-block bucket histogram ----------------
__global__ __launch_bounds__(256) void k_bhist(const void* __restrict__ ei,
                                               const int* __restrict__ flag,
                                               int* __restrict__ bhist) {
    __shared__ int h[NBUCK];
    for (int i = threadIdx.x; i < NBUCK; i += 256) h[i] = 0;
    __syncthreads();
    int is64 = *flag;
    int base = blockIdx.x * CHUNK;
    for (int i = threadIdx.x; i < CHUNK; i += 256)
        atomicAdd(&h[edge_dst(ei, is64, base + i) >> BSHIFT], 1);
    __syncthreads();
    for (int i = threadIdx.x; i < NBUCK; i += 256)
        bhist[i * NBLK_P + blockIdx.x] = h[i];
}

// ---------------- pass 2a: bucket totals -> exclusive bucket starts ----------------
__global__ __launch_bounds__(512) void k_bstart(const int* __restrict__ bhist,
                                                int* __restrict__ bstart) {
    __shared__ int sd[512];
    int t = threadIdx.x;
    int s = 0;
    if (t < NBUCK) {
        const int* p = bhist + t * NBLK_P;
        for (int i = 0; i < NBLK_P; ++i) s += p[i];
    }
    sd[t] = s;
    __syncthreads();
    for (int off = 1; off < 512; off <<= 1) {
        int add = (t >= off) ? sd[t - off] : 0;
        __syncthreads();
        sd[t] += add;
        __syncthreads();
    }
    if (t < NBUCK) bstart[t] = sd[t] - s;
    if (t == 0) bstart[NBUCK] = N_EDGES;
}

// ---------------- pass 2b: per-bucket scan of per-block counts ----------------
__global__ __launch_bounds__(128) void k_boffs(int* __restrict__ bhist,
                                               const int* __restrict__ bstart) {
    __shared__ int sd[128];
    int b = blockIdx.x, t = threadIdx.x;
    int v = bhist[b * NBLK_P + t];
    sd[t] = v;
    __syncthreads();
    for (int off = 1; off < 128; off <<= 1) {
        int add = (t >= off) ? sd[t - off] : 0;
        __syncthreads();
        sd[t] += add;
        __syncthreads();
    }
    bhist[b * NBLK_P + t] = bstart[b] + sd[t] - v;
}

// ---------------- pass 3: partition edges into bucket-grouped (src,dst) pairs ----------------
__global__ __launch_bounds__(256) void k_partition(const void* __restrict__ ei,
                                                   const int* __restrict__ flag,
                                                   const int* __restrict__ bhist,
                                                   uint2* __restrict__ pairs) {
    __shared__ int cur[NBUCK];
    for (int i = threadIdx.x; i < NBUCK; i += 256)
        cur[i] = bhist[i * NBLK_P + blockIdx.x];
    __syncthreads();
    int is64 = *flag;
    int base = blockIdx.x * CHUNK;
    for (int i = threadIdx.x; i < CHUNK; i += 256) {
        int e = base + i;
        int s = edge_src(ei, is64, e);
        int d = edge_dst(ei, is64, e);
        int p = atomicAdd(&cur[d >> BSHIFT], 1);
        pairs[p] = make_uint2((unsigned)s, (unsigned)d);
    }
}

// ---------------- pass 4: per-bucket dst counts + dinv ----------------
__global__ __launch_bounds__(256) void k_dcount(const uint2* __restrict__ pairs,
                                                const int* __restrict__ bstart,
                                                int* __restrict__ cnt,
                                                float* __restrict__ dinv) {
    __shared__ int c[256];
    int b = blockIdx.x, t = threadIdx.x;
    c[t] = 0;
    __syncthreads();
    int s0 = bstart[b], s1 = bstart[b + 1];
    int dbase = b << BSHIFT;
    for (int i = s0 + t; i < s1; i += 256)
        atomicAdd(&c[pairs[i].y - dbase], 1);
    __syncthreads();
    int d = dbase + t;
    if (d < N_NODES) {
        cnt[d] = c[t];
        dinv[d] = rsqrtf((float)c[t] + 1.0f);
    }
}

// ---------------- exclusive scan of cnt -> rowstart ----------------
__global__ __launch_bounds__(256) void k_scan_partial(const int* __restrict__ cnt,
                                                      int* __restrict__ bsum) {
    __shared__ int sd[256];
    int t = threadIdx.x;
    int base = blockIdx.x * 1024 + t * 4;
    int s = 0;
#pragma unroll
    for (int c = 0; c < 4; ++c)
        if (base + c < N_NODES) s += cnt[base + c];
    sd[t] = s;
    __syncthreads();
    for (int off = 128; off > 0; off >>= 1) {
        if (t < off) sd[t] += sd[t + off];
        __syncthreads();
    }
    if (t == 0) bsum[blockIdx.x] = sd[0];
}

__global__ void k_scan_bsums(int* __restrict__ bsum) {  // <<<1,128>>>, NB=98
    __shared__ int sd[128];
    int t = threadIdx.x;
    sd[t] = (t < 98) ? bsum[t] : 0;
    __syncthreads();
    for (int off = 1; off < 128; off <<= 1) {
        int add = (t >= off) ? sd[t - off] : 0;
        __syncthreads();
        sd[t] += add;
        __syncthreads();
    }
    if (t < 98) bsum[t] = (t == 0) ? 0 : sd[t - 1];
}

__global__ __launch_bounds__(256) void k_scan_final(const int* __restrict__ cnt,
                                                    const int* __restrict__ bsum,
                                                    int* __restrict__ rowstart) {
    __shared__ int sd[256];
    int t = threadIdx.x;
    int base = blockIdx.x * 1024 + t * 4;
    int v[4];
#pragma unroll
    for (int c = 0; c < 4; ++c)
        v[c] = (base + c < N_NODES) ? cnt[base + c] : 0;
    int tsum = v[0] + v[1] + v[2] + v[3];
    sd[t] = tsum;
    __syncthreads();
    for (int off = 1; off < 256; off <<= 1) {
        int add = (t >= off) ? sd[t - off] : 0;
        __syncthreads();
        sd[t] += add;
        __syncthreads();
    }
    int run = bsum[blockIdx.x] + sd[t] - tsum;
#pragma unroll
    for (int c = 0; c < 4; ++c) {
        if (base + c < N_NODES) rowstart[base + c] = run;
        run += v[c];
    }
    if (blockIdx.x == 0 && t == 0) rowstart[N_NODES] = N_EDGES;
}

// ---------------- pass 5: final CSR placement ----------------
__global__ __launch_bounds__(256) void k_place(const uint2* __restrict__ pairs,
                                               const int* __restrict__ bstart,
                                               const int* __restrict__ rowstart,
                                               int* __restrict__ csr) {
    __shared__ int pos[256];
    int b = blockIdx.x, t = threadIdx.x;
    int dbase = b << BSHIFT;
    int d = dbase + t;
    pos[t] = (d < N_NODES) ? rowstart[d] : 0;
    __syncthreads();
    int s0 = bstart[b], s1 = bstart[b + 1];
    for (int i = s0 + t; i < s1; i += 256) {
        uint2 pr = pairs[i];
        int p = atomicAdd(&pos[pr.y - dbase], 1);
        csr[p] = (int)pr.x;
    }
}

// ---------------- GEMM1 (LDS-tiled): hs1 = (x @ W1) * dinv[row], fp16 out ----
// block = 256 threads, tile 128 nodes x 64 outs, K chunked by 64.
// thread: 8 nodes x 4 outs register block. LDS 49KB -> 3 blocks/CU.
__global__ __launch_bounds__(256) void k_gemm1(const float* __restrict__ x,
                                               const float* __restrict__ W1,
                                               const float* __restrict__ dinv,
                                               __half* __restrict__ hs1) {
    __shared__ float xsT[64 * XS_LD];   // k-major: xsT[k*132 + n], 33.8 KB
    __shared__ float ws[64 * 64];       // ws[k*64 + j], 16 KB
    int t = threadIdx.x;
    int nblock = blockIdx.x * G1_TM;
    int ng = t >> 4, og = t & 15;
    int n0 = ng * 8, j0 = og * 4;
    float acc[8][4] = {};

    int snode = nblock + (t >> 1);        // staging: thread loads half a row
    int koff = (t & 1) * 32;
    int nl = t >> 1;

    for (int chunk = 0; chunk < 2; ++chunk) {
        int kbase = chunk * 64;
        // stage x (transposed into k-major LDS)
        {
            float4 v[8];
            if (snode < N_NODES) {
                const float4* src = (const float4*)(x + (size_t)snode * F_IN + kbase + koff);
#pragma unroll
                for (int c = 0; c < 8; ++c) v[c] = src[c];
            } else {
#pragma unroll
                for (int c = 0; c < 8; ++c) v[c] = make_float4(0.f, 0.f, 0.f, 0.f);
            }
#pragma unroll
            for (int c = 0; c < 8; ++c) {
                int k = koff + c * 4;
                xsT[(k + 0) * XS_LD + nl] = v[c].x;
                xsT[(k + 1) * XS_LD + nl] = v[c].y;
                xsT[(k + 2) * XS_LD + nl] = v[c].z;
                xsT[(k + 3) * XS_LD + nl] = v[c].w;
            }
        }
        // stage W1 chunk (rows kbase..kbase+63 are contiguous, row-major copy)
        {
            const float4* wsrc = (const float4*)(W1 + kbase * F_HID);
            float4* wdst = (float4*)ws;
#pragma unroll
            for (int c = 0; c < 4; ++c) wdst[c * 256 + t] = wsrc[c * 256 + t];
        }
        __syncthreads();

#pragma unroll 4
        for (int k = 0; k < 64; ++k) {
            const float4* xr = (const float4*)(xsT + k * XS_LD + n0);
            float4 a0 = xr[0], a1 = xr[1];
            float4 bv = *(const float4*)(ws + k * 64 + j0);
            float a[8] = {a0.x, a0.y, a0.z, a0.w, a1.x, a1.y, a1.z, a1.w};
            float bb[4] = {bv.x, bv.y, bv.z, bv.w};
#pragma unroll
            for (int i = 0; i < 8; ++i)
#pragma unroll
                for (int j = 0; j < 4; ++j)
                    acc[i][j] += a[i] * bb[j];
        }
        __syncthreads();
    }

    // epilogue: scale by dinv, convert fp16, store 8B per node
#pragma unroll
    for (int i = 0; i < 8; ++i) {
        int node = nblock + n0 + i;
        if (node < N_NODES) {
            float dv = dinv[node];
            union { __half2 h[2]; float2 f; } u;
            u.h[0] = __floats2half2_rn(acc[i][0] * dv, acc[i][1] * dv);
            u.h[1] = __floats2half2_rn(acc[i][2] * dv, acc[i][3] * dv);
            *(float2*)(hs1 + (size_t)node * F_HID + j0) = u.f;
        }
    }
}

// ---------------- gather layer 1: wave per node, lane = feature ----------------
__global__ __launch_bounds__(256) void k_gather1(const __half* __restrict__ hs1,
                                                 const int* __restrict__ csr,
                                                 const int* __restrict__ rowstart,
                                                 const float* __restrict__ dinv,
                                                 const float* __restrict__ b1,
                                                 float* __restrict__ out1) {
    int w = threadIdx.x >> 6;
    int lane = threadIdx.x & 63;
    int n = blockIdx.x * 4 + w;
    int s0 = rowstart[n], s1 = rowstart[n + 1];
    float acc = __half2float(hs1[(size_t)n * F_HID + lane]);  // self-loop
    int e = s0;
    for (; e + 4 <= s1; e += 4) {
        int a = csr[e], b = csr[e + 1], c = csr[e + 2], d = csr[e + 3];
        float va = __half2float(hs1[(size_t)a * F_HID + lane]);
        float vb = __half2float(hs1[(size_t)b * F_HID + lane]);
        float vc = __half2float(hs1[(size_t)c * F_HID + lane]);
        float vd = __half2float(hs1[(size_t)d * F_HID + lane]);
        acc += va + vb + vc + vd;
    }
    for (; e < s1; ++e)
        acc += __half2float(hs1[(size_t)csr[e] * F_HID + lane]);
    float o = dinv[n] * acc + b1[lane];
    out1[(size_t)n * F_HID + lane] = fmaxf(0.f, o);
}

// ---------------- GEMM2: hs2 = (out1 @ W2) * dinv[row], fp16 out, W2 in LDS ----
__global__ __launch_bounds__(256) void k_gemm2(const float* __restrict__ h,
                                               const float* __restrict__ W2,
                                               const float* __restrict__ dinv,
                                               __half* __restrict__ hs2) {
    __shared__ float ws[F_HID * F_OUT];   // 4 KB
    int t = threadIdx.x;
    ((float4*)ws)[t] = ((const float4*)W2)[t];   // 256 float4 = whole W2
    __syncthreads();
    int tid = blockIdx.x * 256 + t;
    int n = tid >> 2;
    if (n >= N_NODES) return;
    int cq = (tid & 3) << 2;
    const float4* h4 = (const float4*)(h + (size_t)n * F_HID);
    float4 acc = make_float4(0.f, 0.f, 0.f, 0.f);
#pragma unroll 4
    for (int k4 = 0; k4 < 16; ++k4) {
        float4 hv = h4[k4];
        float4 w0 = *(const float4*)(ws + (k4 * 4 + 0) * F_OUT + cq);
        float4 w1 = *(const float4*)(ws + (k4 * 4 + 1) * F_OUT + cq);
        float4 w2 = *(const float4*)(ws + (k4 * 4 + 2) * F_OUT + cq);
        float4 w3 = *(const float4*)(ws + (k4 * 4 + 3) * F_OUT + cq);
        acc.x += hv.x * w0.x + hv.y * w1.x + hv.z * w2.x + hv.w * w3.x;
        acc.y += hv.x * w0.y + hv.y * w1.y + hv.z * w2.y + hv.w * w3.y;
        acc.z += hv.x * w0.z + hv.y * w1.z + hv.z * w2.z + hv.w * w3.z;
        acc.w += hv.x * w0.w + hv.y * w1.w + hv.z * w2.w + hv.w * w3.w;
    }
    float dv = dinv[n];
    union { __half2 h2[2]; float2 f; } u;
    u.h2[0] = __floats2half2_rn(acc.x * dv, acc.y * dv);
    u.h2[1] = __floats2half2_rn(acc.z * dv, acc.w * dv);
    *(float2*)(hs2 + (size_t)n * F_OUT + cq) = u.f;
}

// ---------------- gather layer 2: wave per node, 4 edges x 16 feats ----------------
__global__ __launch_bounds__(256) void k_gather2(const __half* __restrict__ hs2,
                                                 const int* __restrict__ csr,
                                                 const int* __restrict__ rowstart,
                                                 const float* __restrict__ dinv,
                                                 const float* __restrict__ b2,
                                                 float* __restrict__ out) {
    int w = threadIdx.x >> 6;
    int lane = threadIdx.x & 63;
    int n = blockIdx.x * 4 + w;
    int esub = lane >> 4;
    int c = lane & 15;
    int s0 = rowstart[n], s1 = rowstart[n + 1];
    float acc = 0.f;
    for (int e = s0 + esub; e < s1; e += 4) {
        int s = csr[e];
        acc += __half2float(hs2[(size_t)s * F_OUT + c]);
    }
    acc += __shfl_xor(acc, 16);
    acc += __shfl_xor(acc, 32);
    if (lane < 16) {
        float self = __half2float(hs2[(size_t)n * F_OUT + c]);
        out[(size_t)n * F_OUT + c] = dinv[n] * (acc + self) + b2[c];
    }
}

extern "C" void kernel_launch(void* const* d_in, const int* in_sizes, int n_in,
                              void* d_out, int out_size, void* d_ws, size_t ws_size,
                              hipStream_t stream) {
    const float* x  = (const float*)d_in[0];
    const void*  ei = d_in[1];
    const float* W1 = (const float*)d_in[2];
    const float* b1 = (const float*)d_in[3];
    const float* W2 = (const float*)d_in[4];
    const float* b2 = (const float*)d_in[5];
    float* out = (float*)d_out;

    char* ws = (char*)d_ws;
    int*    cnt      = (int*)(ws + OFF_CNT);
    int*    rowstart = (int*)(ws + OFF_ROWSTART);
    float*  dinv     = (float*)(ws + OFF_DINV);
    int*    bsum     = (int*)(ws + OFF_BSUM);
    int*    flag     = (int*)(ws + OFF_FLAG);
    int*    bstart   = (int*)(ws + OFF_BSTART);
    int*    bhist    = (int*)(ws + OFF_BHIST);
    int*    csr      = (int*)(ws + OFF_CSR);
    __half* hs1      = (__half*)(ws + OFF_HS1);
    float*  out1     = (float*)(ws + OFF_OUT1);
    __half* hs2      = (__half*)(ws + OFF_HS2);
    uint2*  pairs    = (uint2*)(ws + OFF_PAIRS);   // aliases out1 (dead until gather1)

    k_detect<<<1, 1, 0, stream>>>(ei, flag);

    // CSR build: bucket partition (no global atomics, coalesced writes)
    k_bhist    <<<NBLK_P, 256, 0, stream>>>(ei, flag, bhist);
    k_bstart   <<<1, 512, 0, stream>>>(bhist, bstart);
    k_boffs    <<<NBUCK, 128, 0, stream>>>(bhist, bstart);
    k_partition<<<NBLK_P, 256, 0, stream>>>(ei, flag, bhist, pairs);
    k_dcount   <<<NBUCK, 256, 0, stream>>>(pairs, bstart, cnt, dinv);
    k_scan_partial<<<98, 256, 0, stream>>>(cnt, bsum);
    k_scan_bsums  <<<1, 128, 0, stream>>>(bsum);
    k_scan_final  <<<98, 256, 0, stream>>>(cnt, bsum, rowstart);
    k_place    <<<NBUCK, 256, 0, stream>>>(pairs, bstart, rowstart, csr);

    // GCN layers
    k_gemm1  <<<G1_BLOCKS, 256, 0, stream>>>(x, W1, dinv, hs1);
    k_gather1<<<N_NODES / 4, 256, 0, stream>>>(hs1, csr, rowstart, dinv, b1, out1);
    k_gemm2  <<<(N_NODES * 4 + 255) / 256, 256, 0, stream>>>(out1, W2, dinv, hs2);
    k_gather2<<<N_NODES / 4, 256, 0, stream>>>(hs2, csr, rowstart, dinv, b2, out);
}

// Round 4
// 401.568 us; speedup vs baseline: 1.8279x; 1.1518x over previous
//
#include <hip/hip_runtime.h>
#include <hip/hip_fp16.h>
#include <stdint.h>

#define N_NODES   100000
#define N_TAB     (N_NODES + 1)   // +1 sentinel zero-row for CSR padding
#define N_EDGES   3200000
#define F_IN      128
#define F_HID     64
#define F_OUT     16

// bucket partition params
#define BSHIFT    8
#define NBUCK     391                  // ceil(100000 / 256)
#define NBLK_P    512                  // partition blocks
#define CHUNK_E   (N_EDGES / NBLK_P)   // 6250 edges per block

// gemm1 tiling
#define G1_TM     128
#define G1_BLOCKS ((N_TAB + G1_TM - 1) / G1_TM)   // 782
#define XS_LD     132

#define CSR_CAP   3500000              // E + 3*N worst-case padding

// ---- workspace layout (bytes), 16B-aligned ----
#define OFF_CNT      0                 // int[N]
#define OFF_ROWSTART 400000            // int[N+1] (padded rowstarts, mult of 4)
#define OFF_DINV     800016            // float[N+1]
#define OFF_BSUM     1200032           // int[128]
#define OFF_FLAG     1200544           // int
#define OFF_BSTART   1200560           // int[NBUCK+1]
#define OFF_BTOT     1202128           // int[NBUCK+pad]
#define OFF_BHIST    1203728           // int[NBUCK*NBLK_P]
#define OFF_CSR      2004496           // int[CSR_CAP]
#define OFF_HS1      16004496          // half[4][N_TAB][16]  (chunk-major!)
#define OFF_OUT1     28804624          // float[N*64]
#define OFF_HS2      54404624          // half[N_TAB*16]
#define OFF_PAIRS    OFF_OUT1          // uint[E] — aliases out1 (dead by then)
// total 57,604,656 bytes

// ---------------- edge dtype detection + loaders ----------------
__global__ void k_detect(const void* __restrict__ ei, int* __restrict__ flag) {
    const unsigned* u = (const unsigned*)ei;
    int ok = 1;
    for (int i = 0; i < 64; ++i) {
        unsigned lo = u[2 * i], hi = u[2 * i + 1];
        if (hi != 0u || lo >= 100000u) { ok = 0; break; }
    }
    *flag = ok;   // 1 => int64 edge data
}

__device__ __forceinline__ int edge_src(const void* ei, int is64, int e) {
    return is64 ? (int)((const long long*)ei)[e] : ((const int*)ei)[e];
}
__device__ __forceinline__ int edge_dst(const void* ei, int is64, int e) {
    return is64 ? (int)((const long long*)ei)[N_EDGES + e]
                : ((const int*)ei)[N_EDGES + e];
}

// ---------------- pass 1: per-block bucket histogram ----------------
__global__ __launch_bounds__(256) void k_bhist(const void* __restrict__ ei,
                                               const int* __restrict__ flag,
                                               int* __restrict__ bhist) {
    __shared__ int h[NBUCK];
    for (int i = threadIdx.x; i < NBUCK; i += 256) h[i] = 0;
    __syncthreads();
    int is64 = *flag;
    int base = blockIdx.x * CHUNK_E;
    for (int i = threadIdx.x; i < CHUNK_E; i += 256)
        atomicAdd(&h[edge_dst(ei, is64, base + i) >> BSHIFT], 1);
    __syncthreads();
    for (int i = threadIdx.x; i < NBUCK; i += 256)
        bhist[i * NBLK_P + blockIdx.x] = h[i];
}

// ---------------- pass 2a: per-bucket totals ----------------
__global__ __launch_bounds__(128) void k_btotal(const int* __restrict__ bhist,
                                                int* __restrict__ btot) {
    __shared__ int sd[128];
    int b = blockIdx.x, t = threadIdx.x;
    const int* p = bhist + b * NBLK_P;
    int s = p[t] + p[t + 128] + p[t + 256] + p[t + 384];
    sd[t] = s;
    __syncthreads();
    for (int off = 64; off > 0; off >>= 1) {
        if (t < off) sd[t] += sd[t + off];
        __syncthreads();
    }
    if (t == 0) btot[b] = sd[0];
}

// ---------------- pass 2b: scan bucket totals -> bucket starts ----------------
__global__ __launch_bounds__(512) void k_bscan(const int* __restrict__ btot,
                                               int* __restrict__ bstart) {
    __shared__ int sd[512];
    int t = threadIdx.x;
    int v = (t < NBUCK) ? btot[t] : 0;
    sd[t] = v;
    __syncthreads();
    for (int off = 1; off < 512; off <<= 1) {
        int a = (t >= off) ? sd[t - off] : 0;
        __syncthreads();
        sd[t] += a;
        __syncthreads();
    }
    if (t < NBUCK) bstart[t] = sd[t] - v;
    if (t == 0) bstart[NBUCK] = N_EDGES;
}

// ---------------- pass 2c: per-bucket scan of per-block counts ----------------
__global__ __launch_bounds__(512) void k_boffs(int* __restrict__ bhist,
                                               const int* __restrict__ bstart) {
    __shared__ int sd[512];
    int b = blockIdx.x, t = threadIdx.x;
    int v = bhist[b * NBLK_P + t];
    sd[t] = v;
    __syncthreads();
    for (int off = 1; off < 512; off <<= 1) {
        int a = (t >= off) ? sd[t - off] : 0;
        __syncthreads();
        sd[t] += a;
        __syncthreads();
    }
    bhist[b * NBLK_P + t] = bstart[b] + sd[t] - v;
}

// ---------------- pass 3: partition into bucket-grouped packed pairs ----------------
__global__ __launch_bounds__(256) void k_partition(const void* __restrict__ ei,
                                                   const int* __restrict__ flag,
                                                   const int* __restrict__ bhist,
                                                   unsigned* __restrict__ pairs) {
    __shared__ int cur[NBUCK];
    for (int i = threadIdx.x; i < NBUCK; i += 256)
        cur[i] = bhist[i * NBLK_P + blockIdx.x];
    __syncthreads();
    int is64 = *flag;
    int base = blockIdx.x * CHUNK_E;
    for (int i = threadIdx.x; i < CHUNK_E; i += 256) {
        int e = base + i;
        int s = edge_src(ei, is64, e);
        int d = edge_dst(ei, is64, e);
        int p = atomicAdd(&cur[d >> BSHIFT], 1);
        pairs[p] = ((unsigned)s << 8) | (unsigned)(d & 255);
    }
}

// ---------------- pass 4: per-bucket dst counts + dinv ----------------
__global__ __launch_bounds__(256) void k_dcount(const unsigned* __restrict__ pairs,
                                                const int* __restrict__ bstart,
                                                int* __restrict__ cnt,
                                                float* __restrict__ dinv) {
    __shared__ int c[256];
    int b = blockIdx.x, t = threadIdx.x;
    c[t] = 0;
    __syncthreads();
    int s0 = bstart[b], s1 = bstart[b + 1];
    for (int i = s0 + t; i < s1; i += 256)
        atomicAdd(&c[pairs[i] & 255u], 1);
    __syncthreads();
    int d = (b << BSHIFT) + t;
    if (d < N_NODES) {
        cnt[d] = c[t];
        dinv[d] = rsqrtf((float)c[t] + 1.0f);
    } else if (d == N_NODES) {
        dinv[d] = 0.f;   // sentinel
    }
}

// ---------------- exclusive scan of PADDED cnt -> rowstart ----------------
__global__ __launch_bounds__(256) void k_scan_partial(const int* __restrict__ cnt,
                                                      int* __restrict__ bsum) {
    __shared__ int sd[256];
    int t = threadIdx.x;
    int base = blockIdx.x * 1024 + t * 4;
    int s = 0;
#pragma unroll
    for (int c = 0; c < 4; ++c)
        if (base + c < N_NODES) s += (cnt[base + c] + 3) & ~3;
    sd[t] = s;
    __syncthreads();
    for (int off = 128; off > 0; off >>= 1) {
        if (t < off) sd[t] += sd[t + off];
        __syncthreads();
    }
    if (t == 0) bsum[blockIdx.x] = sd[0];
}

__global__ void k_scan_bsums(int* __restrict__ bsum) {  // <<<1,128>>>, NB=98
    __shared__ int sd[128];
    int t = threadIdx.x;
    sd[t] = (t < 98) ? bsum[t] : 0;
    __syncthreads();
    for (int off = 1; off < 128; off <<= 1) {
        int add = (t >= off) ? sd[t - off] : 0;
        __syncthreads();
        sd[t] += add;
        __syncthreads();
    }
    if (t < 98) bsum[t] = (t == 0) ? 0 : sd[t - 1];
}

__global__ __launch_bounds__(256) void k_scan_final(const int* __restrict__ cnt,
                                                    const int* __restrict__ bsum,
                                                    int* __restrict__ rowstart) {
    __shared__ int sd[256];
    int t = threadIdx.x;
    int base = blockIdx.x * 1024 + t * 4;
    int v[4];
#pragma unroll
    for (int c = 0; c < 4; ++c)
        v[c] = (base + c < N_NODES) ? ((cnt[base + c] + 3) & ~3) : 0;
    int tsum = v[0] + v[1] + v[2] + v[3];
    sd[t] = tsum;
    __syncthreads();
    for (int off = 1; off < 256; off <<= 1) {
        int add = (t >= off) ? sd[t - off] : 0;
        __syncthreads();
        sd[t] += add;
        __syncthreads();
    }
    int run = bsum[blockIdx.x] + sd[t] - tsum;
#pragma unroll
    for (int c = 0; c < 4; ++c) {
        if (base + c < N_NODES) rowstart[base + c] = run;
        run += v[c];
        if (base + c == N_NODES - 1) rowstart[N_NODES] = run;
    }
}

// ---------------- pass 5: sentinel-fill + CSR placement ----------------
__global__ __launch_bounds__(256) void k_place(const unsigned* __restrict__ pairs,
                                               const int* __restrict__ bstart,
                                               const int* __restrict__ rowstart,
                                               int* __restrict__ csr) {
    __shared__ int pos[256];
    int b = blockIdx.x, t = threadIdx.x;
    int dbase = b << BSHIFT;
    int d = dbase + t;
    pos[t] = (d < N_NODES) ? rowstart[d] : 0;
    int hiIdx = dbase + 256; if (hiIdx > N_NODES) hiIdx = N_NODES;
    int lo = rowstart[dbase], hi = rowstart[hiIdx];
    for (int i = lo + t; i < hi; i += 256) csr[i] = N_NODES;  // sentinel pad
    __syncthreads();
    int s0 = bstart[b], s1 = bstart[b + 1];
    for (int i = s0 + t; i < s1; i += 256) {
        unsigned pr = pairs[i];
        int p = atomicAdd(&pos[pr & 255u], 1);
        csr[p] = (int)(pr >> 8);
    }
}

// ---------------- GEMM1 (LDS-tiled): hs1[chunk][node][16] = (x@W1)*dinv ----
__global__ __launch_bounds__(256) void k_gemm1(const float* __restrict__ x,
                                               const float* __restrict__ W1,
                                               const float* __restrict__ dinv,
                                               __half* __restrict__ hs1) {
    __shared__ float xsT[64 * XS_LD];
    __shared__ float ws[64 * 64];
    int t = threadIdx.x;
    int nblock = blockIdx.x * G1_TM;
    int ng = t >> 4, og = t & 15;
    int n0 = ng * 8;
    float acc[8][4] = {};

    int snode = nblock + (t >> 1);
    int koff = (t & 1) * 32;
    int nl = t >> 1;

    for (int chunk = 0; chunk < 2; ++chunk) {
        int kbase = chunk * 64;
        {
            float4 v[8];
            if (snode < N_NODES) {
                const float4* src = (const float4*)(x + (size_t)snode * F_IN + kbase + koff);
#pragma unroll
                for (int c = 0; c < 8; ++c) v[c] = src[c];
            } else {
#pragma unroll
                for (int c = 0; c < 8; ++c) v[c] = make_float4(0.f, 0.f, 0.f, 0.f);
            }
#pragma unroll
            for (int c = 0; c < 8; ++c) {
                int k = koff + c * 4;
                xsT[(k + 0) * XS_LD + nl] = v[c].x;
                xsT[(k + 1) * XS_LD + nl] = v[c].y;
                xsT[(k + 2) * XS_LD + nl] = v[c].z;
                xsT[(k + 3) * XS_LD + nl] = v[c].w;
            }
        }
        {
            const float4* wsrc = (const float4*)(W1 + kbase * F_HID);
            float4* wdst = (float4*)ws;
#pragma unroll
            for (int c = 0; c < 4; ++c) wdst[c * 256 + t] = wsrc[c * 256 + t];
        }
        __syncthreads();

#pragma unroll 4
        for (int k = 0; k < 64; ++k) {
            const float4* xr = (const float4*)(xsT + k * XS_LD + n0);
            float4 a0 = xr[0], a1 = xr[1];
            float4 bv = *(const float4*)(ws + k * 64 + og * 4);
            float a[8] = {a0.x, a0.y, a0.z, a0.w, a1.x, a1.y, a1.z, a1.w};
            float bb[4] = {bv.x, bv.y, bv.z, bv.w};
#pragma unroll
            for (int i = 0; i < 8; ++i)
#pragma unroll
                for (int j = 0; j < 4; ++j)
                    acc[i][j] += a[i] * bb[j];
        }
        __syncthreads();
    }

    // epilogue: chunk-major layout hs1[(og>>2)*N_TAB + node][16] + (og&3)*4
#pragma unroll
    for (int i = 0; i < 8; ++i) {
        int node = nblock + n0 + i;
        if (node < N_TAB) {
            float dv = dinv[node];   // dinv[N_NODES]=0 -> sentinel row zeros
            union { __half2 h[2]; float2 f; } u;
            u.h[0] = __floats2half2_rn(acc[i][0] * dv, acc[i][1] * dv);
            u.h[1] = __floats2half2_rn(acc[i][2] * dv, acc[i][3] * dv);
            *(float2*)(hs1 + ((size_t)(og >> 2) * N_TAB + node) * 16 + (og & 3) * 4) = u.f;
        }
    }
}

// ---------------- aggregate layer 1: 4 feature-chunk passes in one launch ----
// chunk = bid/25000 keeps each 3.2MB table pass L2-resident.
// wave = node; lanes = 4 edge-slots x 16 feats; 16 edges/iter via int4 csr.
__global__ __launch_bounds__(256) void k_agg1(const __half* __restrict__ hs1,
                                              const int* __restrict__ csr,
                                              const int* __restrict__ rowstart,
                                              const float* __restrict__ dinv,
                                              const float* __restrict__ b1,
                                              float* __restrict__ out1) {
    int bid = blockIdx.x;
    int chunk = bid / 25000;
    int nb = bid - chunk * 25000;
    int w = threadIdx.x >> 6, lane = threadIdx.x & 63;
    int n = nb * 4 + w;
    int eslot = lane >> 4, f = lane & 15;
    const __half* T = hs1 + (size_t)chunk * ((size_t)N_TAB * 16);
    int q0 = rowstart[n] >> 2, q1 = rowstart[n + 1] >> 2;
    float acc = 0.f;
    for (int q = q0 + eslot; q < q1; q += 4) {
        int4 c = ((const int4*)csr)[q];
        acc += __half2float(T[c.x * 16 + f]);
        acc += __half2float(T[c.y * 16 + f]);
        acc += __half2float(T[c.z * 16 + f]);
        acc += __half2float(T[c.w * 16 + f]);
    }
    acc += __shfl_xor(acc, 16);
    acc += __shfl_xor(acc, 32);
    if (lane < 16) {
        float self = __half2float(T[n * 16 + f]);
        float o = dinv[n] * (acc + self) + b1[chunk * 16 + f];
        out1[(size_t)n * F_HID + chunk * 16 + f] = fmaxf(o, 0.f);
    }
}

// ---------------- GEMM2: hs2 = (out1 @ W2) * dinv, fp16, W2 in LDS ----------
__global__ __launch_bounds__(256) void k_gemm2(const float* __restrict__ h,
                                               const float* __restrict__ W2,
                                               const float* __restrict__ dinv,
                                               __half* __restrict__ hs2) {
    __shared__ float ws[F_HID * F_OUT];
    int t = threadIdx.x;
    ((float4*)ws)[t] = ((const float4*)W2)[t];
    __syncthreads();
    int tid = blockIdx.x * 256 + t;
    int n = tid >> 2;
    if (n > N_NODES) return;
    int cq = (tid & 3) << 2;
    if (n == N_NODES) {   // sentinel zero row
        *(float2*)(hs2 + (size_t)n * F_OUT + cq) = make_float2(0.f, 0.f);
        return;
    }
    const float4* h4 = (const float4*)(h + (size_t)n * F_HID);
    float4 acc = make_float4(0.f, 0.f, 0.f, 0.f);
#pragma unroll 4
    for (int k4 = 0; k4 < 16; ++k4) {
        float4 hv = h4[k4];
        float4 w0 = *(const float4*)(ws + (k4 * 4 + 0) * F_OUT + cq);
        float4 w1 = *(const float4*)(ws + (k4 * 4 + 1) * F_OUT + cq);
        float4 w2 = *(const float4*)(ws + (k4 * 4 + 2) * F_OUT + cq);
        float4 w3 = *(const float4*)(ws + (k4 * 4 + 3) * F_OUT + cq);
        acc.x += hv.x * w0.x + hv.y * w1.x + hv.z * w2.x + hv.w * w3.x;
        acc.y += hv.x * w0.y + hv.y * w1.y + hv.z * w2.y + hv.w * w3.y;
        acc.z += hv.x * w0.z + hv.y * w1.z + hv.z * w2.z + hv.w * w3.z;
        acc.w += hv.x * w0.w + hv.y * w1.w + hv.z * w2.w + hv.w * w3.w;
    }
    float dv = dinv[n];
    union { __half2 h2[2]; float2 f; } u;
    u.h2[0] = __floats2half2_rn(acc.x * dv, acc.y * dv);
    u.h2[1] = __floats2half2_rn(acc.z * dv, acc.w * dv);
    *(float2*)(hs2 + (size_t)n * F_OUT + cq) = u.f;
}

// ---------------- aggregate layer 2: single pass (table 3.2MB, L2-resident) --
__global__ __launch_bounds__(256) void k_agg2(const __half* __restrict__ hs2,
                                              const int* __restrict__ csr,
                                              const int* __restrict__ rowstart,
                                              const float* __restrict__ dinv,
                                              const float* __restrict__ b2,
                                              float* __restrict__ out) {
    int w = threadIdx.x >> 6, lane = threadIdx.x & 63;
    int n = blockIdx.x * 4 + w;
    int eslot = lane >> 4, f = lane & 15;
    int q0 = rowstart[n] >> 2, q1 = rowstart[n + 1] >> 2;
    float acc = 0.f;
    for (int q = q0 + eslot; q < q1; q += 4) {
        int4 c = ((const int4*)csr)[q];
        acc += __half2float(hs2[c.x * 16 + f]);
        acc += __half2float(hs2[c.y * 16 + f]);
        acc += __half2float(hs2[c.z * 16 + f]);
        acc += __half2float(hs2[c.w * 16 + f]);
    }
    acc += __shfl_xor(acc, 16);
    acc += __shfl_xor(acc, 32);
    if (lane < 16) {
        float self = __half2float(hs2[n * 16 + f]);
        out[(size_t)n * F_OUT + f] = dinv[n] * (acc + self) + b2[f];
    }
}

extern "C" void kernel_launch(void* const* d_in, const int* in_sizes, int n_in,
                              void* d_out, int out_size, void* d_ws, size_t ws_size,
                              hipStream_t stream) {
    const float* x  = (const float*)d_in[0];
    const void*  ei = d_in[1];
    const float* W1 = (const float*)d_in[2];
    const float* b1 = (const float*)d_in[3];
    const float* W2 = (const float*)d_in[4];
    const float* b2 = (const float*)d_in[5];
    float* out = (float*)d_out;

    char* ws = (char*)d_ws;
    int*      cnt      = (int*)(ws + OFF_CNT);
    int*      rowstart = (int*)(ws + OFF_ROWSTART);
    float*    dinv     = (float*)(ws + OFF_DINV);
    int*      bsum     = (int*)(ws + OFF_BSUM);
    int*      flag     = (int*)(ws + OFF_FLAG);
    int*      bstart   = (int*)(ws + OFF_BSTART);
    int*      btot     = (int*)(ws + OFF_BTOT);
    int*      bhist    = (int*)(ws + OFF_BHIST);
    int*      csr      = (int*)(ws + OFF_CSR);
    __half*   hs1      = (__half*)(ws + OFF_HS1);
    float*    out1     = (float*)(ws + OFF_OUT1);
    __half*   hs2      = (__half*)(ws + OFF_HS2);
    unsigned* pairs    = (unsigned*)(ws + OFF_PAIRS);

    k_detect<<<1, 1, 0, stream>>>(ei, flag);

    // CSR build (padded rows, sentinel = N_NODES)
    k_bhist    <<<NBLK_P, 256, 0, stream>>>(ei, flag, bhist);
    k_btotal   <<<NBUCK, 128, 0, stream>>>(bhist, btot);
    k_bscan    <<<1, 512, 0, stream>>>(btot, bstart);
    k_boffs    <<<NBUCK, 512, 0, stream>>>(bhist, bstart);
    k_partition<<<NBLK_P, 256, 0, stream>>>(ei, flag, bhist, pairs);
    k_dcount   <<<NBUCK, 256, 0, stream>>>(pairs, bstart, cnt, dinv);
    k_scan_partial<<<98, 256, 0, stream>>>(cnt, bsum);
    k_scan_bsums  <<<1, 128, 0, stream>>>(bsum);
    k_scan_final  <<<98, 256, 0, stream>>>(cnt, bsum, rowstart);
    k_place    <<<NBUCK, 256, 0, stream>>>(pairs, bstart, rowstart, csr);

    // GCN layers
    k_gemm1<<<G1_BLOCKS, 256, 0, stream>>>(x, W1, dinv, hs1);
    k_agg1 <<<4 * 25000, 256, 0, stream>>>(hs1, csr, rowstart, dinv, b1, out1);
    k_gemm2<<<(N_TAB * 4 + 255) / 256, 256, 0, stream>>>(out1, W2, dinv, hs2);
    k_agg2 <<<25000, 256, 0, stream>>>(hs2, csr, rowstart, dinv, b2, out);
}

// Round 5
// 392.216 us; speedup vs baseline: 1.8715x; 1.0238x over previous
//
#include <hip/hip_runtime.h>
#include <hip/hip_fp16.h>
#include <stdint.h>

#define N_NODES   100000
#define N_TAB     (N_NODES + 1)   // +1 sentinel zero-row for CSR padding
#define N_EDGES   3200000
#define F_IN      128
#define F_HID     64
#define F_OUT     16

typedef _Float16 h2v __attribute__((ext_vector_type(2)));

// bucket partition params
#define BSHIFT    8
#define NBUCK     391                  // ceil(100000 / 256)
#define NBLK_P    512                  // partition blocks
#define CHUNK_E   (N_EDGES / NBLK_P)   // 6250 edges per block

// gemm1 tiling
#define G1_TM     128
#define G1_BLOCKS ((N_TAB + G1_TM - 1) / G1_TM)   // 782
#define XS_LD     132

#define CSR_CAP   3500000              // E + 3*N worst-case padding

// ---- workspace layout (bytes), 16B-aligned ----
#define OFF_CNT      0                 // int[N]
#define OFF_ROWSTART 400000            // int[N+1] (padded rowstarts, mult of 4)
#define OFF_DINV     800016            // float[N+1]
#define OFF_BSUM     1200032           // int[128]
#define OFF_FLAG     1200544           // int
#define OFF_BSTART   1200560           // int[NBUCK+1]
#define OFF_BTOT     1202128           // int[NBUCK+pad]
#define OFF_BHIST    1203728           // int[NBUCK*NBLK_P]
#define OFF_CSR      2004496           // int[CSR_CAP]
#define OFF_HS1      16004496          // half[4][N_TAB][16]  (chunk-major)
#define OFF_OUT1     28804624          // float[N*64]
#define OFF_HS2      54404624          // half[N_TAB*16]
#define OFF_PAIRS    OFF_OUT1          // uint[E] — aliases out1 (dead by then)

// ---------------- edge dtype detection + loaders ----------------
__global__ void k_detect(const void* __restrict__ ei, int* __restrict__ flag) {
    const unsigned* u = (const unsigned*)ei;
    int ok = 1;
    for (int i = 0; i < 64; ++i) {
        unsigned lo = u[2 * i], hi = u[2 * i + 1];
        if (hi != 0u || lo >= 100000u) { ok = 0; break; }
    }
    *flag = ok;   // 1 => int64 edge data
}

__device__ __forceinline__ int edge_src(const void* ei, int is64, int e) {
    return is64 ? (int)((const long long*)ei)[e] : ((const int*)ei)[e];
}
__device__ __forceinline__ int edge_dst(const void* ei, int is64, int e) {
    return is64 ? (int)((const long long*)ei)[N_EDGES + e]
                : ((const int*)ei)[N_EDGES + e];
}

// ---------------- pass 1: per-block bucket histogram ----------------
__global__ __launch_bounds__(256) void k_bhist(const void* __restrict__ ei,
                                               const int* __restrict__ flag,
                                               int* __restrict__ bhist) {
    __shared__ int h[NBUCK];
    for (int i = threadIdx.x; i < NBUCK; i += 256) h[i] = 0;
    __syncthreads();
    int is64 = *flag;
    int base = blockIdx.x * CHUNK_E;
    for (int i = threadIdx.x; i < CHUNK_E; i += 256)
        atomicAdd(&h[edge_dst(ei, is64, base + i) >> BSHIFT], 1);
    __syncthreads();
    for (int i = threadIdx.x; i < NBUCK; i += 256)
        bhist[i * NBLK_P + blockIdx.x] = h[i];
}

// ---------------- pass 2a: per-bucket totals ----------------
__global__ __launch_bounds__(128) void k_btotal(const int* __restrict__ bhist,
                                                int* __restrict__ btot) {
    __shared__ int sd[128];
    int b = blockIdx.x, t = threadIdx.x;
    const int* p = bhist + b * NBLK_P;
    int s = p[t] + p[t + 128] + p[t + 256] + p[t + 384];
    sd[t] = s;
    __syncthreads();
    for (int off = 64; off > 0; off >>= 1) {
        if (t < off) sd[t] += sd[t + off];
        __syncthreads();
    }
    if (t == 0) btot[b] = sd[0];
}

// ---------------- pass 2b: scan bucket totals -> bucket starts ----------------
__global__ __launch_bounds__(512) void k_bscan(const int* __restrict__ btot,
                                               int* __restrict__ bstart) {
    __shared__ int sd[512];
    int t = threadIdx.x;
    int v = (t < NBUCK) ? btot[t] : 0;
    sd[t] = v;
    __syncthreads();
    for (int off = 1; off < 512; off <<= 1) {
        int a = (t >= off) ? sd[t - off] : 0;
        __syncthreads();
        sd[t] += a;
        __syncthreads();
    }
    if (t < NBUCK) bstart[t] = sd[t] - v;
    if (t == 0) bstart[NBUCK] = N_EDGES;
}

// ---------------- pass 2c: per-bucket scan of per-block counts ----------------
__global__ __launch_bounds__(512) void k_boffs(int* __restrict__ bhist,
                                               const int* __restrict__ bstart) {
    __shared__ int sd[512];
    int b = blockIdx.x, t = threadIdx.x;
    int v = bhist[b * NBLK_P + t];
    sd[t] = v;
    __syncthreads();
    for (int off = 1; off < 512; off <<= 1) {
        int a = (t >= off) ? sd[t - off] : 0;
        __syncthreads();
        sd[t] += a;
        __syncthreads();
    }
    bhist[b * NBLK_P + t] = bstart[b] + sd[t] - v;
}

// ---------------- pass 3: partition into bucket-grouped packed pairs ----------------
__global__ __launch_bounds__(256) void k_partition(const void* __restrict__ ei,
                                                   const int* __restrict__ flag,
                                                   const int* __restrict__ bhist,
                                                   unsigned* __restrict__ pairs) {
    __shared__ int cur[NBUCK];
    for (int i = threadIdx.x; i < NBUCK; i += 256)
        cur[i] = bhist[i * NBLK_P + blockIdx.x];
    __syncthreads();
    int is64 = *flag;
    int base = blockIdx.x * CHUNK_E;
    for (int i = threadIdx.x; i < CHUNK_E; i += 256) {
        int e = base + i;
        int s = edge_src(ei, is64, e);
        int d = edge_dst(ei, is64, e);
        int p = atomicAdd(&cur[d >> BSHIFT], 1);
        pairs[p] = ((unsigned)s << 8) | (unsigned)(d & 255);
    }
}

// ---------------- pass 4: per-bucket dst counts + dinv ----------------
__global__ __launch_bounds__(256) void k_dcount(const unsigned* __restrict__ pairs,
                                                const int* __restrict__ bstart,
                                                int* __restrict__ cnt,
                                                float* __restrict__ dinv) {
    __shared__ int c[256];
    int b = blockIdx.x, t = threadIdx.x;
    c[t] = 0;
    __syncthreads();
    int s0 = bstart[b], s1 = bstart[b + 1];
    for (int i = s0 + t; i < s1; i += 256)
        atomicAdd(&c[pairs[i] & 255u], 1);
    __syncthreads();
    int d = (b << BSHIFT) + t;
    if (d < N_NODES) {
        cnt[d] = c[t];
        dinv[d] = rsqrtf((float)c[t] + 1.0f);
    } else if (d == N_NODES) {
        dinv[d] = 0.f;   // sentinel
    }
}

// ---------------- exclusive scan of PADDED cnt -> rowstart ----------------
__global__ __launch_bounds__(256) void k_scan_partial(const int* __restrict__ cnt,
                                                      int* __restrict__ bsum) {
    __shared__ int sd[256];
    int t = threadIdx.x;
    int base = blockIdx.x * 1024 + t * 4;
    int s = 0;
#pragma unroll
    for (int c = 0; c < 4; ++c)
        if (base + c < N_NODES) s += (cnt[base + c] + 3) & ~3;
    sd[t] = s;
    __syncthreads();
    for (int off = 128; off > 0; off >>= 1) {
        if (t < off) sd[t] += sd[t + off];
        __syncthreads();
    }
    if (t == 0) bsum[blockIdx.x] = sd[0];
}

__global__ void k_scan_bsums(int* __restrict__ bsum) {  // <<<1,128>>>, NB=98
    __shared__ int sd[128];
    int t = threadIdx.x;
    sd[t] = (t < 98) ? bsum[t] : 0;
    __syncthreads();
    for (int off = 1; off < 128; off <<= 1) {
        int add = (t >= off) ? sd[t - off] : 0;
        __syncthreads();
        sd[t] += add;
        __syncthreads();
    }
    if (t < 98) bsum[t] = (t == 0) ? 0 : sd[t - 1];
}

__global__ __launch_bounds__(256) void k_scan_final(const int* __restrict__ cnt,
                                                    const int* __restrict__ bsum,
                                                    int* __restrict__ rowstart) {
    __shared__ int sd[256];
    int t = threadIdx.x;
    int base = blockIdx.x * 1024 + t * 4;
    int v[4];
#pragma unroll
    for (int c = 0; c < 4; ++c)
        v[c] = (base + c < N_NODES) ? ((cnt[base + c] + 3) & ~3) : 0;
    int tsum = v[0] + v[1] + v[2] + v[3];
    sd[t] = tsum;
    __syncthreads();
    for (int off = 1; off < 256; off <<= 1) {
        int add = (t >= off) ? sd[t - off] : 0;
        __syncthreads();
        sd[t] += add;
        __syncthreads();
    }
    int run = bsum[blockIdx.x] + sd[t] - tsum;
#pragma unroll
    for (int c = 0; c < 4; ++c) {
        if (base + c < N_NODES) rowstart[base + c] = run;
        run += v[c];
        if (base + c == N_NODES - 1) rowstart[N_NODES] = run;
    }
}

// ---------------- pass 5: sentinel-fill + CSR placement ----------------
__global__ __launch_bounds__(256) void k_place(const unsigned* __restrict__ pairs,
                                               const int* __restrict__ bstart,
                                               const int* __restrict__ rowstart,
                                               int* __restrict__ csr) {
    __shared__ int pos[256];
    int b = blockIdx.x, t = threadIdx.x;
    int dbase = b << BSHIFT;
    int d = dbase + t;
    pos[t] = (d < N_NODES) ? rowstart[d] : 0;
    int hiIdx = dbase + 256; if (hiIdx > N_NODES) hiIdx = N_NODES;
    int lo = rowstart[dbase], hi = rowstart[hiIdx];
    for (int i = lo + t; i < hi; i += 256) csr[i] = N_NODES;  // sentinel pad
    __syncthreads();
    int s0 = bstart[b], s1 = bstart[b + 1];
    for (int i = s0 + t; i < s1; i += 256) {
        unsigned pr = pairs[i];
        int p = atomicAdd(&pos[pr & 255u], 1);
        csr[p] = (int)(pr >> 8);
    }
}

// ---------------- GEMM1 (LDS-tiled): hs1[chunk][node][16] = (x@W1)*dinv ----
__global__ __launch_bounds__(256) void k_gemm1(const float* __restrict__ x,
                                               const float* __restrict__ W1,
                                               const float* __restrict__ dinv,
                                               __half* __restrict__ hs1) {
    __shared__ float xsT[64 * XS_LD];
    __shared__ float ws[64 * 64];
    int t = threadIdx.x;
    int nblock = blockIdx.x * G1_TM;
    int ng = t >> 4, og = t & 15;
    int n0 = ng * 8;
    float acc[8][4] = {};

    int snode = nblock + (t >> 1);
    int koff = (t & 1) * 32;
    int nl = t >> 1;

    for (int chunk = 0; chunk < 2; ++chunk) {
        int kbase = chunk * 64;
        {
            float4 v[8];
            if (snode < N_NODES) {
                const float4* src = (const float4*)(x + (size_t)snode * F_IN + kbase + koff);
#pragma unroll
                for (int c = 0; c < 8; ++c) v[c] = src[c];
            } else {
#pragma unroll
                for (int c = 0; c < 8; ++c) v[c] = make_float4(0.f, 0.f, 0.f, 0.f);
            }
#pragma unroll
            for (int c = 0; c < 8; ++c) {
                int k = koff + c * 4;
                xsT[(k + 0) * XS_LD + nl] = v[c].x;
                xsT[(k + 1) * XS_LD + nl] = v[c].y;
                xsT[(k + 2) * XS_LD + nl] = v[c].z;
                xsT[(k + 3) * XS_LD + nl] = v[c].w;
            }
        }
        {
            const float4* wsrc = (const float4*)(W1 + kbase * F_HID);
            float4* wdst = (float4*)ws;
#pragma unroll
            for (int c = 0; c < 4; ++c) wdst[c * 256 + t] = wsrc[c * 256 + t];
        }
        __syncthreads();

#pragma unroll 4
        for (int k = 0; k < 64; ++k) {
            const float4* xr = (const float4*)(xsT + k * XS_LD + n0);
            float4 a0 = xr[0], a1 = xr[1];
            float4 bv = *(const float4*)(ws + k * 64 + og * 4);
            float a[8] = {a0.x, a0.y, a0.z, a0.w, a1.x, a1.y, a1.z, a1.w};
            float bb[4] = {bv.x, bv.y, bv.z, bv.w};
#pragma unroll
            for (int i = 0; i < 8; ++i)
#pragma unroll
                for (int j = 0; j < 4; ++j)
                    acc[i][j] += a[i] * bb[j];
        }
        __syncthreads();
    }

    // epilogue: chunk-major layout hs1[(og>>2)*N_TAB + node][16] + (og&3)*4
#pragma unroll
    for (int i = 0; i < 8; ++i) {
        int node = nblock + n0 + i;
        if (node < N_TAB) {
            float dv = dinv[node];   // dinv[N_NODES]=0 -> sentinel row zeros
            union { __half2 h[2]; float2 f; } u;
            u.h[0] = __floats2half2_rn(acc[i][0] * dv, acc[i][1] * dv);
            u.h[1] = __floats2half2_rn(acc[i][2] * dv, acc[i][3] * dv);
            *(float2*)(hs1 + ((size_t)(og >> 2) * N_TAB + node) * 16 + (og & 3) * 4) = u.f;
        }
    }
}

// ---------------- aggregate layer 1: 4 L2-resident passes, packed fp16 adds --
// lane = slot(8) x featpair(8). Each lane: 1 dword load (2 halfs) + 1 pk_add
// per edge. Slot-reduce in fp32 at the end. 4 passes via bid/25000.
__global__ __launch_bounds__(256) void k_agg1(const __half* __restrict__ hs1,
                                              const int* __restrict__ csr,
                                              const int* __restrict__ rowstart,
                                              const float* __restrict__ dinv,
                                              const float* __restrict__ b1,
                                              float* __restrict__ out1) {
    int bid = blockIdx.x;
    int chunk = bid / 25000;
    int nb = bid - chunk * 25000;
    int w = threadIdx.x >> 6, lane = threadIdx.x & 63;
    int n = nb * 4 + w;
    int slot = lane >> 3, fp = lane & 7;
    const char* T = (const char*)(hs1 + (size_t)chunk * ((size_t)N_TAB * 16));
    unsigned fo = fp * 4u;
    int q0 = rowstart[n] >> 2, q1 = rowstart[n + 1] >> 2;
    h2v acc = {(_Float16)0.f, (_Float16)0.f};
    for (int q = q0 + slot; q < q1; q += 8) {
        int4 c = ((const int4*)csr)[q];
        acc += *(const h2v*)(T + ((unsigned)c.x * 32u + fo));
        acc += *(const h2v*)(T + ((unsigned)c.y * 32u + fo));
        acc += *(const h2v*)(T + ((unsigned)c.z * 32u + fo));
        acc += *(const h2v*)(T + ((unsigned)c.w * 32u + fo));
    }
    float sx = (float)acc.x, sy = (float)acc.y;
    sx += __shfl_xor(sx, 8);  sy += __shfl_xor(sy, 8);
    sx += __shfl_xor(sx, 16); sy += __shfl_xor(sy, 16);
    sx += __shfl_xor(sx, 32); sy += __shfl_xor(sy, 32);
    if (lane < 8) {
        h2v self = *(const h2v*)(T + ((unsigned)n * 32u + fo));
        float dv = dinv[n];
        int fb = chunk * 16 + fp * 2;
        float ox = fmaxf(dv * (sx + (float)self.x) + b1[fb], 0.f);
        float oy = fmaxf(dv * (sy + (float)self.y) + b1[fb + 1], 0.f);
        *(float2*)(out1 + (size_t)n * F_HID + fb) = make_float2(ox, oy);
    }
}

// ---------------- GEMM2: hs2 = (out1 @ W2) * dinv, fp16, W2 in LDS ----------
__global__ __launch_bounds__(256) void k_gemm2(const float* __restrict__ h,
                                               const float* __restrict__ W2,
                                               const float* __restrict__ dinv,
                                               __half* __restrict__ hs2) {
    __shared__ float ws[F_HID * F_OUT];
    int t = threadIdx.x;
    ((float4*)ws)[t] = ((const float4*)W2)[t];
    __syncthreads();
    int tid = blockIdx.x * 256 + t;
    int n = tid >> 2;
    if (n > N_NODES) return;
    int cq = (tid & 3) << 2;
    if (n == N_NODES) {   // sentinel zero row
        *(float2*)(hs2 + (size_t)n * F_OUT + cq) = make_float2(0.f, 0.f);
        return;
    }
    const float4* h4 = (const float4*)(h + (size_t)n * F_HID);
    float4 acc = make_float4(0.f, 0.f, 0.f, 0.f);
#pragma unroll 4
    for (int k4 = 0; k4 < 16; ++k4) {
        float4 hv = h4[k4];
        float4 w0 = *(const float4*)(ws + (k4 * 4 + 0) * F_OUT + cq);
        float4 w1 = *(const float4*)(ws + (k4 * 4 + 1) * F_OUT + cq);
        float4 w2 = *(const float4*)(ws + (k4 * 4 + 2) * F_OUT + cq);
        float4 w3 = *(const float4*)(ws + (k4 * 4 + 3) * F_OUT + cq);
        acc.x += hv.x * w0.x + hv.y * w1.x + hv.z * w2.x + hv.w * w3.x;
        acc.y += hv.x * w0.y + hv.y * w1.y + hv.z * w2.y + hv.w * w3.y;
        acc.z += hv.x * w0.z + hv.y * w1.z + hv.z * w2.z + hv.w * w3.z;
        acc.w += hv.x * w0.w + hv.y * w1.w + hv.z * w2.w + hv.w * w3.w;
    }
    float dv = dinv[n];
    union { __half2 h2[2]; float2 f; } u;
    u.h2[0] = __floats2half2_rn(acc.x * dv, acc.y * dv);
    u.h2[1] = __floats2half2_rn(acc.z * dv, acc.w * dv);
    *(float2*)(hs2 + (size_t)n * F_OUT + cq) = u.f;
}

// ---------------- aggregate layer 2: single pass, packed fp16 adds ----------
__global__ __launch_bounds__(256) void k_agg2(const __half* __restrict__ hs2,
                                              const int* __restrict__ csr,
                                              const int* __restrict__ rowstart,
                                              const float* __restrict__ dinv,
                                              const float* __restrict__ b2,
                                              float* __restrict__ out) {
    int w = threadIdx.x >> 6, lane = threadIdx.x & 63;
    int n = blockIdx.x * 4 + w;
    int slot = lane >> 3, fp = lane & 7;
    const char* T = (const char*)hs2;
    unsigned fo = fp * 4u;
    int q0 = rowstart[n] >> 2, q1 = rowstart[n + 1] >> 2;
    h2v acc = {(_Float16)0.f, (_Float16)0.f};
    for (int q = q0 + slot; q < q1; q += 8) {
        int4 c = ((const int4*)csr)[q];
        acc += *(const h2v*)(T + ((unsigned)c.x * 32u + fo));
        acc += *(const h2v*)(T + ((unsigned)c.y * 32u + fo));
        acc += *(const h2v*)(T + ((unsigned)c.z * 32u + fo));
        acc += *(const h2v*)(T + ((unsigned)c.w * 32u + fo));
    }
    float sx = (float)acc.x, sy = (float)acc.y;
    sx += __shfl_xor(sx, 8);  sy += __shfl_xor(sy, 8);
    sx += __shfl_xor(sx, 16); sy += __shfl_xor(sy, 16);
    sx += __shfl_xor(sx, 32); sy += __shfl_xor(sy, 32);
    if (lane < 8) {
        h2v self = *(const h2v*)(T + ((unsigned)n * 32u + fo));
        float dv = dinv[n];
        int fb = fp * 2;
        float ox = dv * (sx + (float)self.x) + b2[fb];
        float oy = dv * (sy + (float)self.y) + b2[fb + 1];
        *(float2*)(out + (size_t)n * F_OUT + fb) = make_float2(ox, oy);
    }
}

extern "C" void kernel_launch(void* const* d_in, const int* in_sizes, int n_in,
                              void* d_out, int out_size, void* d_ws, size_t ws_size,
                              hipStream_t stream) {
    const float* x  = (const float*)d_in[0];
    const void*  ei = d_in[1];
    const float* W1 = (const float*)d_in[2];
    const float* b1 = (const float*)d_in[3];
    const float* W2 = (const float*)d_in[4];
    const float* b2 = (const float*)d_in[5];
    float* out = (float*)d_out;

    char* ws = (char*)d_ws;
    int*      cnt      = (int*)(ws + OFF_CNT);
    int*      rowstart = (int*)(ws + OFF_ROWSTART);
    float*    dinv     = (float*)(ws + OFF_DINV);
    int*      bsum     = (int*)(ws + OFF_BSUM);
    int*      flag     = (int*)(ws + OFF_FLAG);
    int*      bstart   = (int*)(ws + OFF_BSTART);
    int*      btot     = (int*)(ws + OFF_BTOT);
    int*      bhist    = (int*)(ws + OFF_BHIST);
    int*      csr      = (int*)(ws + OFF_CSR);
    __half*   hs1      = (__half*)(ws + OFF_HS1);
    float*    out1     = (float*)(ws + OFF_OUT1);
    __half*   hs2      = (__half*)(ws + OFF_HS2);
    unsigned* pairs    = (unsigned*)(ws + OFF_PAIRS);

    k_detect<<<1, 1, 0, stream>>>(ei, flag);

    // CSR build (padded rows, sentinel = N_NODES)
    k_bhist    <<<NBLK_P, 256, 0, stream>>>(ei, flag, bhist);
    k_btotal   <<<NBUCK, 128, 0, stream>>>(bhist, btot);
    k_bscan    <<<1, 512, 0, stream>>>(btot, bstart);
    k_boffs    <<<NBUCK, 512, 0, stream>>>(bhist, bstart);
    k_partition<<<NBLK_P, 256, 0, stream>>>(ei, flag, bhist, pairs);
    k_dcount   <<<NBUCK, 256, 0, stream>>>(pairs, bstart, cnt, dinv);
    k_scan_partial<<<98, 256, 0, stream>>>(cnt, bsum);
    k_scan_bsums  <<<1, 128, 0, stream>>>(bsum);
    k_scan_final  <<<98, 256, 0, stream>>>(cnt, bsum, rowstart);
    k_place    <<<NBUCK, 256, 0, stream>>>(pairs, bstart, rowstart, csr);

    // GCN layers
    k_gemm1<<<G1_BLOCKS, 256, 0, stream>>>(x, W1, dinv, hs1);
    k_agg1 <<<4 * 25000, 256, 0, stream>>>(hs1, csr, rowstart, dinv, b1, out1);
    k_gemm2<<<(N_TAB * 4 + 255) / 256, 256, 0, stream>>>(out1, W2, dinv, hs2);
    k_agg2 <<<25000, 256, 0, stream>>>(hs2, csr, rowstart, dinv, b2, out);
}

// Round 6
// 379.179 us; speedup vs baseline: 1.9359x; 1.0344x over previous
//
#include <hip/hip_runtime.h>
#include <hip/hip_fp16.h>
#include <stdint.h>

#define N_NODES   100000
#define N_TAB     (N_NODES + 1)   // +1 sentinel zero-row for CSR padding
#define N_EDGES   3200000
#define F_IN      128
#define F_HID     64
#define F_OUT     16

typedef _Float16 h2v __attribute__((ext_vector_type(2)));

// bucket partition params
#define BSHIFT    8
#define NBUCK     391                  // ceil(100000 / 256)
#define NBLK_P    512                  // partition blocks
#define CHUNK_E   (N_EDGES / NBLK_P)   // 6250 edges per block

// gemm1 tiling
#define G1_TM     128
#define G1_BLOCKS ((N_TAB + G1_TM - 1) / G1_TM)   // 782
#define XS_LD     132

#define CSR_CAP   3500000              // E + 3*N worst-case padding

// ---- workspace layout (bytes), 16B-aligned ----
#define OFF_CNT      0                 // int[N]
#define OFF_ROWSTART 400000            // int[N+1] (padded rowstarts, mult of 4)
#define OFF_DINV     800016            // float[N+1]
#define OFF_BSUM     1200032           // int[128]
#define OFF_FLAG     1200544           // int
#define OFF_BSTART   1200560           // int[NBUCK+1]
#define OFF_BTOT     1202128           // int[NBUCK+pad]
#define OFF_BHIST    1203728           // int[NBUCK*NBLK_P]
#define OFF_CSR      2004496           // int[CSR_CAP]
#define OFF_HS1      16004496          // half[4][N_TAB][16]  (chunk-major)
#define OFF_OUT1     28804624          // float[N*64]
#define OFF_HS2      54404624          // half[N_TAB*16]
#define OFF_PAIRS    OFF_OUT1          // uint[E] — aliases out1 (dead by then)

// ---------------- edge dtype detection + loaders ----------------
__global__ void k_detect(const void* __restrict__ ei, int* __restrict__ flag) {
    const unsigned* u = (const unsigned*)ei;
    int ok = 1;
    for (int i = 0; i < 64; ++i) {
        unsigned lo = u[2 * i], hi = u[2 * i + 1];
        if (hi != 0u || lo >= 100000u) { ok = 0; break; }
    }
    *flag = ok;   // 1 => int64 edge data
}

__device__ __forceinline__ int edge_src(const void* ei, int is64, int e) {
    return is64 ? (int)((const long long*)ei)[e] : ((const int*)ei)[e];
}
__device__ __forceinline__ int edge_dst(const void* ei, int is64, int e) {
    return is64 ? (int)((const long long*)ei)[N_EDGES + e]
                : ((const int*)ei)[N_EDGES + e];
}

// ---------------- pass 1: per-block bucket histogram ----------------
__global__ __launch_bounds__(256) void k_bhist(const void* __restrict__ ei,
                                               const int* __restrict__ flag,
                                               int* __restrict__ bhist) {
    __shared__ int h[NBUCK];
    for (int i = threadIdx.x; i < NBUCK; i += 256) h[i] = 0;
    __syncthreads();
    int is64 = *flag;
    int base = blockIdx.x * CHUNK_E;
    for (int i = threadIdx.x; i < CHUNK_E; i += 256)
        atomicAdd(&h[edge_dst(ei, is64, base + i) >> BSHIFT], 1);
    __syncthreads();
    for (int i = threadIdx.x; i < NBUCK; i += 256)
        bhist[i * NBLK_P + blockIdx.x] = h[i];
}

// ---------------- pass 2a: per-bucket totals ----------------
__global__ __launch_bounds__(128) void k_btotal(const int* __restrict__ bhist,
                                                int* __restrict__ btot) {
    __shared__ int sd[128];
    int b = blockIdx.x, t = threadIdx.x;
    const int* p = bhist + b * NBLK_P;
    int s = p[t] + p[t + 128] + p[t + 256] + p[t + 384];
    sd[t] = s;
    __syncthreads();
    for (int off = 64; off > 0; off >>= 1) {
        if (t < off) sd[t] += sd[t + off];
        __syncthreads();
    }
    if (t == 0) btot[b] = sd[0];
}

// ---------------- pass 2b: scan bucket totals -> bucket starts ----------------
__global__ __launch_bounds__(512) void k_bscan(const int* __restrict__ btot,
                                               int* __restrict__ bstart) {
    __shared__ int sd[512];
    int t = threadIdx.x;
    int v = (t < NBUCK) ? btot[t] : 0;
    sd[t] = v;
    __syncthreads();
    for (int off = 1; off < 512; off <<= 1) {
        int a = (t >= off) ? sd[t - off] : 0;
        __syncthreads();
        sd[t] += a;
        __syncthreads();
    }
    if (t < NBUCK) bstart[t] = sd[t] - v;
    if (t == 0) bstart[NBUCK] = N_EDGES;
}

// ---------------- pass 2c: per-bucket scan of per-block counts ----------------
__global__ __launch_bounds__(512) void k_boffs(int* __restrict__ bhist,
                                               const int* __restrict__ bstart) {
    __shared__ int sd[512];
    int b = blockIdx.x, t = threadIdx.x;
    int v = bhist[b * NBLK_P + t];
    sd[t] = v;
    __syncthreads();
    for (int off = 1; off < 512; off <<= 1) {
        int a = (t >= off) ? sd[t - off] : 0;
        __syncthreads();
        sd[t] += a;
        __syncthreads();
    }
    bhist[b * NBLK_P + t] = bstart[b] + sd[t] - v;
}

// ---------------- pass 3: partition into bucket-grouped packed pairs ----------------
__global__ __launch_bounds__(256) void k_partition(const void* __restrict__ ei,
                                                   const int* __restrict__ flag,
                                                   const int* __restrict__ bhist,
                                                   unsigned* __restrict__ pairs) {
    __shared__ int cur[NBUCK];
    for (int i = threadIdx.x; i < NBUCK; i += 256)
        cur[i] = bhist[i * NBLK_P + blockIdx.x];
    __syncthreads();
    int is64 = *flag;
    int base = blockIdx.x * CHUNK_E;
    for (int i = threadIdx.x; i < CHUNK_E; i += 256) {
        int e = base + i;
        int s = edge_src(ei, is64, e);
        int d = edge_dst(ei, is64, e);
        int p = atomicAdd(&cur[d >> BSHIFT], 1);
        pairs[p] = ((unsigned)s << 8) | (unsigned)(d & 255);
    }
}

// ---------------- pass 4: per-bucket dst counts + dinv ----------------
__global__ __launch_bounds__(256) void k_dcount(const unsigned* __restrict__ pairs,
                                                const int* __restrict__ bstart,
                                                int* __restrict__ cnt,
                                                float* __restrict__ dinv) {
    __shared__ int c[256];
    int b = blockIdx.x, t = threadIdx.x;
    c[t] = 0;
    __syncthreads();
    int s0 = bstart[b], s1 = bstart[b + 1];
    for (int i = s0 + t; i < s1; i += 256)
        atomicAdd(&c[pairs[i] & 255u], 1);
    __syncthreads();
    int d = (b << BSHIFT) + t;
    if (d < N_NODES) {
        cnt[d] = c[t];
        dinv[d] = rsqrtf((float)c[t] + 1.0f);
    } else if (d == N_NODES) {
        dinv[d] = 0.f;   // sentinel
    }
}

// ---------------- exclusive scan of PADDED cnt -> rowstart ----------------
__global__ __launch_bounds__(256) void k_scan_partial(const int* __restrict__ cnt,
                                                      int* __restrict__ bsum) {
    __shared__ int sd[256];
    int t = threadIdx.x;
    int base = blockIdx.x * 1024 + t * 4;
    int s = 0;
#pragma unroll
    for (int c = 0; c < 4; ++c)
        if (base + c < N_NODES) s += (cnt[base + c] + 3) & ~3;
    sd[t] = s;
    __syncthreads();
    for (int off = 128; off > 0; off >>= 1) {
        if (t < off) sd[t] += sd[t + off];
        __syncthreads();
    }
    if (t == 0) bsum[blockIdx.x] = sd[0];
}

__global__ void k_scan_bsums(int* __restrict__ bsum) {  // <<<1,128>>>, NB=98
    __shared__ int sd[128];
    int t = threadIdx.x;
    sd[t] = (t < 98) ? bsum[t] : 0;
    __syncthreads();
    for (int off = 1; off < 128; off <<= 1) {
        int add = (t >= off) ? sd[t - off] : 0;
        __syncthreads();
        sd[t] += add;
        __syncthreads();
    }
    if (t < 98) bsum[t] = (t == 0) ? 0 : sd[t - 1];
}

__global__ __launch_bounds__(256) void k_scan_final(const int* __restrict__ cnt,
                                                    const int* __restrict__ bsum,
                                                    int* __restrict__ rowstart) {
    __shared__ int sd[256];
    int t = threadIdx.x;
    int base = blockIdx.x * 1024 + t * 4;
    int v[4];
#pragma unroll
    for (int c = 0; c < 4; ++c)
        v[c] = (base + c < N_NODES) ? ((cnt[base + c] + 3) & ~3) : 0;
    int tsum = v[0] + v[1] + v[2] + v[3];
    sd[t] = tsum;
    __syncthreads();
    for (int off = 1; off < 256; off <<= 1) {
        int add = (t >= off) ? sd[t - off] : 0;
        __syncthreads();
        sd[t] += add;
        __syncthreads();
    }
    int run = bsum[blockIdx.x] + sd[t] - tsum;
#pragma unroll
    for (int c = 0; c < 4; ++c) {
        if (base + c < N_NODES) rowstart[base + c] = run;
        run += v[c];
        if (base + c == N_NODES - 1) rowstart[N_NODES] = run;
    }
}

// ---------------- pass 5: sentinel-fill + CSR placement ----------------
__global__ __launch_bounds__(256) void k_place(const unsigned* __restrict__ pairs,
                                               const int* __restrict__ bstart,
                                               const int* __restrict__ rowstart,
                                               int* __restrict__ csr) {
    __shared__ int pos[256];
    int b = blockIdx.x, t = threadIdx.x;
    int dbase = b << BSHIFT;
    int d = dbase + t;
    pos[t] = (d < N_NODES) ? rowstart[d] : 0;
    int hiIdx = dbase + 256; if (hiIdx > N_NODES) hiIdx = N_NODES;
    int lo = rowstart[dbase], hi = rowstart[hiIdx];
    for (int i = lo + t; i < hi; i += 256) csr[i] = N_NODES;  // sentinel pad
    __syncthreads();
    int s0 = bstart[b], s1 = bstart[b + 1];
    for (int i = s0 + t; i < s1; i += 256) {
        unsigned pr = pairs[i];
        int p = atomicAdd(&pos[pr & 255u], 1);
        csr[p] = (int)(pr >> 8);
    }
}

// ---------------- GEMM1 (LDS-tiled): hs1[chunk][node][16] = (x@W1)*dinv ----
__global__ __launch_bounds__(256) void k_gemm1(const float* __restrict__ x,
                                               const float* __restrict__ W1,
                                               const float* __restrict__ dinv,
                                               __half* __restrict__ hs1) {
    __shared__ float xsT[64 * XS_LD];
    __shared__ float ws[64 * 64];
    int t = threadIdx.x;
    int nblock = blockIdx.x * G1_TM;
    int ng = t >> 4, og = t & 15;
    int n0 = ng * 8;
    float acc[8][4] = {};

    int snode = nblock + (t >> 1);
    int koff = (t & 1) * 32;
    int nl = t >> 1;

    for (int chunk = 0; chunk < 2; ++chunk) {
        int kbase = chunk * 64;
        {
            float4 v[8];
            if (snode < N_NODES) {
                const float4* src = (const float4*)(x + (size_t)snode * F_IN + kbase + koff);
#pragma unroll
                for (int c = 0; c < 8; ++c) v[c] = src[c];
            } else {
#pragma unroll
                for (int c = 0; c < 8; ++c) v[c] = make_float4(0.f, 0.f, 0.f, 0.f);
            }
#pragma unroll
            for (int c = 0; c < 8; ++c) {
                int k = koff + c * 4;
                xsT[(k + 0) * XS_LD + nl] = v[c].x;
                xsT[(k + 1) * XS_LD + nl] = v[c].y;
                xsT[(k + 2) * XS_LD + nl] = v[c].z;
                xsT[(k + 3) * XS_LD + nl] = v[c].w;
            }
        }
        {
            const float4* wsrc = (const float4*)(W1 + kbase * F_HID);
            float4* wdst = (float4*)ws;
#pragma unroll
            for (int c = 0; c < 4; ++c) wdst[c * 256 + t] = wsrc[c * 256 + t];
        }
        __syncthreads();

#pragma unroll 4
        for (int k = 0; k < 64; ++k) {
            const float4* xr = (const float4*)(xsT + k * XS_LD + n0);
            float4 a0 = xr[0], a1 = xr[1];
            float4 bv = *(const float4*)(ws + k * 64 + og * 4);
            float a[8] = {a0.x, a0.y, a0.z, a0.w, a1.x, a1.y, a1.z, a1.w};
            float bb[4] = {bv.x, bv.y, bv.z, bv.w};
#pragma unroll
            for (int i = 0; i < 8; ++i)
#pragma unroll
                for (int j = 0; j < 4; ++j)
                    acc[i][j] += a[i] * bb[j];
        }
        __syncthreads();
    }

    // epilogue: chunk-major layout hs1[(og>>2)*N_TAB + node][16] + (og&3)*4
#pragma unroll
    for (int i = 0; i < 8; ++i) {
        int node = nblock + n0 + i;
        if (node < N_TAB) {
            float dv = dinv[node];   // dinv[N_NODES]=0 -> sentinel row zeros
            union { __half2 h[2]; float2 f; } u;
            u.h[0] = __floats2half2_rn(acc[i][0] * dv, acc[i][1] * dv);
            u.h[1] = __floats2half2_rn(acc[i][2] * dv, acc[i][3] * dv);
            *(float2*)(hs1 + ((size_t)(og >> 2) * N_TAB + node) * 16 + (og & 3) * 4) = u.f;
        }
    }
}

// ---------------- aggregate layer 1: 4 L2-resident chunk passes -------------
// wave = 8 nodes (slot) x 8 featpairs (fp). Each slot walks its own node's
// quad list; no cross-lane reduction; all 64 lanes live in the epilogue.
// Two interleaved fp16 accumulators bound the fp16 add-chain error.
__global__ __launch_bounds__(256) void k_agg1(const __half* __restrict__ hs1,
                                              const int* __restrict__ csr,
                                              const int* __restrict__ rowstart,
                                              const float* __restrict__ dinv,
                                              const float* __restrict__ b1,
                                              float* __restrict__ out1) {
    int bid = blockIdx.x;            // grid = 4 * 3125
    int chunk = bid / 3125;
    int nb = bid - chunk * 3125;
    int w = threadIdx.x >> 6, lane = threadIdx.x & 63;
    int slot = lane >> 3, fp = lane & 7;
    int n = nb * 32 + w * 8 + slot;  // 3125*32 = 100000 exact
    const char* T = (const char*)(hs1 + (size_t)chunk * ((size_t)N_TAB * 16));
    unsigned fo = fp * 4u;
    int q0 = rowstart[n] >> 2, q1 = rowstart[n + 1] >> 2;
    h2v accA = {(_Float16)0.f, (_Float16)0.f};
    h2v accB = {(_Float16)0.f, (_Float16)0.f};
    for (int q = q0; q < q1; ++q) {
        int4 c = ((const int4*)csr)[q];
        accA += *(const h2v*)(T + ((unsigned)c.x * 32u + fo));
        accB += *(const h2v*)(T + ((unsigned)c.y * 32u + fo));
        accA += *(const h2v*)(T + ((unsigned)c.z * 32u + fo));
        accB += *(const h2v*)(T + ((unsigned)c.w * 32u + fo));
    }
    h2v self = *(const h2v*)(T + ((unsigned)n * 32u + fo));
    float dv = dinv[n];
    int fb = chunk * 16 + fp * 2;
    float sx = (float)accA.x + (float)accB.x + (float)self.x;
    float sy = (float)accA.y + (float)accB.y + (float)self.y;
    float ox = fmaxf(dv * sx + b1[fb], 0.f);
    float oy = fmaxf(dv * sy + b1[fb + 1], 0.f);
    *(float2*)(out1 + (size_t)n * F_HID + fb) = make_float2(ox, oy);
}

// ---------------- GEMM2: hs2 = (out1 @ W2) * dinv, fp16, W2 in LDS ----------
__global__ __launch_bounds__(256) void k_gemm2(const float* __restrict__ h,
                                               const float* __restrict__ W2,
                                               const float* __restrict__ dinv,
                                               __half* __restrict__ hs2) {
    __shared__ float ws[F_HID * F_OUT];
    int t = threadIdx.x;
    ((float4*)ws)[t] = ((const float4*)W2)[t];
    __syncthreads();
    int tid = blockIdx.x * 256 + t;
    int n = tid >> 2;
    if (n > N_NODES) return;
    int cq = (tid & 3) << 2;
    if (n == N_NODES) {   // sentinel zero row
        *(float2*)(hs2 + (size_t)n * F_OUT + cq) = make_float2(0.f, 0.f);
        return;
    }
    const float4* h4 = (const float4*)(h + (size_t)n * F_HID);
    float4 acc = make_float4(0.f, 0.f, 0.f, 0.f);
#pragma unroll 4
    for (int k4 = 0; k4 < 16; ++k4) {
        float4 hv = h4[k4];
        float4 w0 = *(const float4*)(ws + (k4 * 4 + 0) * F_OUT + cq);
        float4 w1 = *(const float4*)(ws + (k4 * 4 + 1) * F_OUT + cq);
        float4 w2 = *(const float4*)(ws + (k4 * 4 + 2) * F_OUT + cq);
        float4 w3 = *(const float4*)(ws + (k4 * 4 + 3) * F_OUT + cq);
        acc.x += hv.x * w0.x + hv.y * w1.x + hv.z * w2.x + hv.w * w3.x;
        acc.y += hv.x * w0.y + hv.y * w1.y + hv.z * w2.y + hv.w * w3.y;
        acc.z += hv.x * w0.z + hv.y * w1.z + hv.z * w2.z + hv.w * w3.z;
        acc.w += hv.x * w0.w + hv.y * w1.w + hv.z * w2.w + hv.w * w3.w;
    }
    float dv = dinv[n];
    union { __half2 h2[2]; float2 f; } u;
    u.h2[0] = __floats2half2_rn(acc.x * dv, acc.y * dv);
    u.h2[1] = __floats2half2_rn(acc.z * dv, acc.w * dv);
    *(float2*)(hs2 + (size_t)n * F_OUT + cq) = u.f;
}

// ---------------- aggregate layer 2: single pass, slot=node layout ----------
__global__ __launch_bounds__(256) void k_agg2(const __half* __restrict__ hs2,
                                              const int* __restrict__ csr,
                                              const int* __restrict__ rowstart,
                                              const float* __restrict__ dinv,
                                              const float* __restrict__ b2,
                                              float* __restrict__ out) {
    int w = threadIdx.x >> 6, lane = threadIdx.x & 63;
    int slot = lane >> 3, fp = lane & 7;
    int n = blockIdx.x * 32 + w * 8 + slot;   // grid = 3125
    const char* T = (const char*)hs2;
    unsigned fo = fp * 4u;
    int q0 = rowstart[n] >> 2, q1 = rowstart[n + 1] >> 2;
    h2v accA = {(_Float16)0.f, (_Float16)0.f};
    h2v accB = {(_Float16)0.f, (_Float16)0.f};
    for (int q = q0; q < q1; ++q) {
        int4 c = ((const int4*)csr)[q];
        accA += *(const h2v*)(T + ((unsigned)c.x * 32u + fo));
        accB += *(const h2v*)(T + ((unsigned)c.y * 32u + fo));
        accA += *(const h2v*)(T + ((unsigned)c.z * 32u + fo));
        accB += *(const h2v*)(T + ((unsigned)c.w * 32u + fo));
    }
    h2v self = *(const h2v*)(T + ((unsigned)n * 32u + fo));
    float dv = dinv[n];
    int fb = fp * 2;
    float sx = (float)accA.x + (float)accB.x + (float)self.x;
    float sy = (float)accA.y + (float)accB.y + (float)self.y;
    float ox = dv * sx + b2[fb];
    float oy = dv * sy + b2[fb + 1];
    *(float2*)(out + (size_t)n * F_OUT + fb) = make_float2(ox, oy);
}

extern "C" void kernel_launch(void* const* d_in, const int* in_sizes, int n_in,
                              void* d_out, int out_size, void* d_ws, size_t ws_size,
                              hipStream_t stream) {
    const float* x  = (const float*)d_in[0];
    const void*  ei = d_in[1];
    const float* W1 = (const float*)d_in[2];
    const float* b1 = (const float*)d_in[3];
    const float* W2 = (const float*)d_in[4];
    const float* b2 = (const float*)d_in[5];
    float* out = (float*)d_out;

    char* ws = (char*)d_ws;
    int*      cnt      = (int*)(ws + OFF_CNT);
    int*      rowstart = (int*)(ws + OFF_ROWSTART);
    float*    dinv     = (float*)(ws + OFF_DINV);
    int*      bsum     = (int*)(ws + OFF_BSUM);
    int*      flag     = (int*)(ws + OFF_FLAG);
    int*      bstart   = (int*)(ws + OFF_BSTART);
    int*      btot     = (int*)(ws + OFF_BTOT);
    int*      bhist    = (int*)(ws + OFF_BHIST);
    int*      csr      = (int*)(ws + OFF_CSR);
    __half*   hs1      = (__half*)(ws + OFF_HS1);
    float*    out1     = (float*)(ws + OFF_OUT1);
    __half*   hs2      = (__half*)(ws + OFF_HS2);
    unsigned* pairs    = (unsigned*)(ws + OFF_PAIRS);

    k_detect<<<1, 1, 0, stream>>>(ei, flag);

    // CSR build (padded rows, sentinel = N_NODES)
    k_bhist    <<<NBLK_P, 256, 0, stream>>>(ei, flag, bhist);
    k_btotal   <<<NBUCK, 128, 0, stream>>>(bhist, btot);
    k_bscan    <<<1, 512, 0, stream>>>(btot, bstart);
    k_boffs    <<<NBUCK, 512, 0, stream>>>(bhist, bstart);
    k_partition<<<NBLK_P, 256, 0, stream>>>(ei, flag, bhist, pairs);
    k_dcount   <<<NBUCK, 256, 0, stream>>>(pairs, bstart, cnt, dinv);
    k_scan_partial<<<98, 256, 0, stream>>>(cnt, bsum);
    k_scan_bsums  <<<1, 128, 0, stream>>>(bsum);
    k_scan_final  <<<98, 256, 0, stream>>>(cnt, bsum, rowstart);
    k_place    <<<NBUCK, 256, 0, stream>>>(pairs, bstart, rowstart, csr);

    // GCN layers
    k_gemm1<<<G1_BLOCKS, 256, 0, stream>>>(x, W1, dinv, hs1);
    k_agg1 <<<4 * 3125, 256, 0, stream>>>(hs1, csr, rowstart, dinv, b1, out1);
    k_gemm2<<<(N_TAB * 4 + 255) / 256, 256, 0, stream>>>(out1, W2, dinv, hs2);
    k_agg2 <<<3125, 256, 0, stream>>>(hs2, csr, rowstart, dinv, b2, out);
}